// Round 3
// baseline (141.846 us; speedup 1.0000x reference)
//
#include <hip/hip_runtime.h>
#include <stdint.h>

#define HW 4194304      // 2048*2048
#define WIDTH 2048
#define F(x) ((float)(x))   // double literal -> f32, exactly like numpy scalar promotion

// ---------------------------------------------------------------------------
// Bit-exact replication of glibc sysdeps/ieee754/flt-32/s_cbrtf.c (pre-2.41)
// — what np.cbrt(float32) resolves to on the host. EMPIRICAL RULE (R2/R5/R6
// vs R3): ALL THREE channels (fx, fy, fz) must use this exact path; any
// deviation in fx/fz fails at absmax 2.73e-2 even though the perturbation
// model says it shouldn't. Do not substitute HW transcendentals here.
// ---------------------------------------------------------------------------
__device__ __forceinline__ float cbrtf_glibc(float x) {
    unsigned int bits = __float_as_uint(x);
    int xe = (int)((bits >> 23) & 0xFF) - 126;
    float xm = __uint_as_float((bits & 0x007FFFFFu) | 0x3F000000u);

    static const double factor[5] = {
        1.0 / 1.5874010519681994748,   // 1 / 2^(2/3)
        1.0 / 1.2599210498948731648,   // 1 / 2^(1/3)
        1.0,
        1.2599210498948731648,         // 2^(1/3)
        1.5874010519681994748          // 2^(2/3)
    };

    double xmd = (double)xm;
    double p = __dsub_rn(0.697570460207922770, __dmul_rn(0.191502161678719066, xmd));
    p = __dadd_rn(0.492659620528969547, __dmul_rn(p, xmd));
    float u = (float)p;

    float t2 = __fmul_rn(__fmul_rn(u, u), u);   // float, two roundings (as glibc)

    double ud  = (double)u;
    double t2d = (double)t2;
    double num = __dmul_rn(ud, __dadd_rn(t2d, __dmul_rn(2.0, xmd)));
    double den = __dadd_rn(__dmul_rn(2.0, t2d), xmd);
    double ym  = __dmul_rn(__ddiv_rn(num, den), factor[2 + (xe % 3)]);
    float ymf = (float)ym;

    return ldexpf(ymf, xe / 3);
}

// Exact forward path — the ONLY forward path (see empirical rule above).
__device__ __forceinline__ void rgb2lab_px(float r, float g, float b,
                                           int& l8, float& A_, float& B_) {
    float X = __fadd_rn(__fadd_rn(__fmul_rn(r, F(0.412453)), __fmul_rn(g, F(0.357580))), __fmul_rn(b, F(0.180423)));
    float Y = __fadd_rn(__fadd_rn(__fmul_rn(r, F(0.212671)), __fmul_rn(g, F(0.715160))), __fmul_rn(b, F(0.072169)));
    float Z = __fadd_rn(__fadd_rn(__fmul_rn(r, F(0.019334)), __fmul_rn(g, F(0.119193))), __fmul_rn(b, F(0.950227)));
    X = __fdiv_rn(X, F(0.950456));
    Z = __fdiv_rn(Z, F(1.088754));
    const float EPS = F(0.008856);
    const float C0  = F(16.0 / 116.0);
    float fx = (X > EPS) ? cbrtf_glibc(X) : __fadd_rn(__fmul_rn(F(7.787), X), C0);
    float fy = (Y > EPS) ? cbrtf_glibc(Y) : __fadd_rn(__fmul_rn(F(7.787), Y), C0);
    float fz = (Z > EPS) ? cbrtf_glibc(Z) : __fadd_rn(__fmul_rn(F(7.787), Z), C0);
    float L  = __fsub_rn(__fmul_rn(F(116.0), fy), F(16.0));
    A_ = __fmul_rn(F(500.0), __fsub_rn(fx, fy));
    B_ = __fmul_rn(F(200.0), __fsub_rn(fy, fz));
    float Lr = rintf(__fmul_rn(L, F(255.0 / 100.0)));
    Lr = fminf(fmaxf(Lr, 0.0f), 255.0f);
    l8 = (int)Lr;
}

// L8 only — Y/fy computed with the IDENTICAL instruction sequence as
// rgb2lab_px (bit-identical bin for every pixel), fx/fz skipped entirely
// (they do not feed L8). The full exact path still runs in K2 for A,B.
__device__ __forceinline__ int l8_of_rgb(float r, float g, float b) {
    float Y = __fadd_rn(__fadd_rn(__fmul_rn(r, F(0.212671)), __fmul_rn(g, F(0.715160))), __fmul_rn(b, F(0.072169)));
    const float EPS = F(0.008856);
    const float C0  = F(16.0 / 116.0);
    float fy = (Y > EPS) ? cbrtf_glibc(Y) : __fadd_rn(__fmul_rn(F(7.787), Y), C0);
    float L  = __fsub_rn(__fmul_rn(F(116.0), fy), F(16.0));
    float Lr = rintf(__fmul_rn(L, F(255.0 / 100.0)));
    Lr = fminf(fmaxf(Lr, 0.0f), 255.0f);
    return (int)Lr;
}

// lab2rgb epilogue (value-returning).
__device__ __forceinline__ void lab2rgb_px(float Leq, float A_, float B_,
                                           float& rr, float& gg, float& bb) {
    const float EPS = F(0.008856);
    const float C0  = F(16.0 / 116.0);
    float fy2 = __fdiv_rn(__fadd_rn(Leq, 16.0f), 116.0f);
    float fx2 = __fadd_rn(fy2, __fdiv_rn(A_, 500.0f));
    float fz2 = __fsub_rn(fy2, __fdiv_rn(B_, 200.0f));
    float t3;
    t3 = fx2 * fx2 * fx2;
    float X = ((t3 > EPS) ? t3 : __fdiv_rn(__fsub_rn(fx2, C0), F(7.787))) * F(0.950456);
    t3 = fy2 * fy2 * fy2;
    float Y = ((t3 > EPS) ? t3 : __fdiv_rn(__fsub_rn(fy2, C0), F(7.787))) * F(1.0);
    t3 = fz2 * fz2 * fz2;
    float Z = ((t3 > EPS) ? t3 : __fdiv_rn(__fsub_rn(fz2, C0), F(7.787))) * F(1.088754);
    rr = __fadd_rn(__fadd_rn(__fmul_rn(X, F(3.240479)),  __fmul_rn(Y, F(-1.537150))), __fmul_rn(Z, F(-0.498535)));
    gg = __fadd_rn(__fadd_rn(__fmul_rn(X, F(-0.969256)), __fmul_rn(Y, F(1.875992))),  __fmul_rn(Z, F(0.041556)));
    bb = __fadd_rn(__fadd_rn(__fmul_rn(X, F(0.055648)),  __fmul_rn(Y, F(-0.204043))), __fmul_rn(Z, F(1.057311)));
    rr = fminf(fmaxf(rr, 0.0f), 1.0f);
    gg = fminf(fmaxf(gg, 0.0f), 1.0f);
    bb = fminf(fmaxf(bb, 0.0f), 1.0f);
}

// ===========================================================================
// K1: histogram only. One block per row; thread t owns cols [8t, 8t+8)
// (float4-vectorized reads). ONE cbrt per pixel (fy path only) — no A/B/l8
// stores, no cross-kernel per-pixel state => no spills, no workspace
// round-trip. LDS-staged per-row histogram, merged to global via atomics.
// ===========================================================================
__global__ __launch_bounds__(256, 4) void k_histY(const float* __restrict__ x,
                                                  unsigned int* __restrict__ hist) {
    __shared__ unsigned int h[2048];
    const int t = threadIdx.x;
    const int y = blockIdx.x;
    #pragma unroll
    for (int i = 0; i < 8; ++i) h[i * 256 + t] = 0;
    __syncthreads();

    const int base = y * WIDTH + t * 8;
    float4 ra = *(const float4*)(x + base);
    float4 rb = *(const float4*)(x + base + 4);
    float4 ga = *(const float4*)(x + base + HW);
    float4 gb = *(const float4*)(x + base + HW + 4);
    float4 ba = *(const float4*)(x + base + 2 * HW);
    float4 bb = *(const float4*)(x + base + 2 * HW + 4);

    // tile index is uniform across the 8 px (t*8..t*8+7 never crosses a
    // 256-px tile boundary)
    const int hb = ((t >> 5) << 8);
    atomicAdd(&h[hb + l8_of_rgb(ra.x, ga.x, ba.x)], 1u);
    atomicAdd(&h[hb + l8_of_rgb(ra.y, ga.y, ba.y)], 1u);
    atomicAdd(&h[hb + l8_of_rgb(ra.z, ga.z, ba.z)], 1u);
    atomicAdd(&h[hb + l8_of_rgb(ra.w, ga.w, ba.w)], 1u);
    atomicAdd(&h[hb + l8_of_rgb(rb.x, gb.x, bb.x)], 1u);
    atomicAdd(&h[hb + l8_of_rgb(rb.y, gb.y, bb.y)], 1u);
    atomicAdd(&h[hb + l8_of_rgb(rb.z, gb.z, bb.z)], 1u);
    atomicAdd(&h[hb + l8_of_rgb(rb.w, gb.w, bb.w)], 1u);

    __syncthreads();
    unsigned int* gh = hist + (y >> 8) * 2048;
    #pragma unroll
    for (int i = 0; i < 8; ++i) {
        unsigned int v = h[i * 256 + t];
        if (v) atomicAdd(&gh[i * 256 + t], v);
    }
}

// ===========================================================================
// K2: per-block LUT build (wave-scan, validated bit-exact in R2) + apply.
// One block per row. The 16 LUTs this row needs (tile-rows y0,y1) are built
// redundantly from the global hist — kills the k_lut kernel, its serial-
// cumsum latency bubble, and one launch boundary. Exactness: all partial
// sums are multiples of 2^-8 bounded by 2^16 => exact in f32 in ANY
// association => identical to the reference serial cumsum.
// ===========================================================================
__global__ __launch_bounds__(256, 4) void k_lut_apply(const float* __restrict__ x,
        const unsigned int* __restrict__ hist,
        float* __restrict__ out) {
    __shared__ float lutS[4096];   // [2][8][256]: tile-row y0, tile-row y1
    const int t = threadIdx.x;
    const int y = blockIdx.x;

    float fyc = fminf(fmaxf(((float)y + 0.5f) * (1.0f / 256.0f) - 0.5f, 0.0f), 7.0f);
    int y0 = (int)floorf(fyc);
    int y1 = min(y0 + 1, 7);
    float wy = __fsub_rn(fyc, (float)y0);
    float omwy = __fsub_rn(1.0f, wy);

    // ---- LUT build: 4 waves x 4 tiles, lane owns 4 bins ----
    {
        const int lane = t & 63;
        const int w = t >> 6;
        #pragma unroll
        for (int i = 0; i < 4; ++i) {
            int gidx = w * 4 + i;             // 0..15
            int trow = gidx >> 3;             // 0 = y0 row, 1 = y1 row
            int tcol = gidx & 7;
            int tile = (trow ? y1 : y0) * 8 + tcol;
            uint4 hv = *(const uint4*)(hist + tile * 256 + lane * 4);
            float h0 = (float)hv.x, h1 = (float)hv.y, h2 = (float)hv.z, h3 = (float)hv.w;
            float e = __fadd_rn(__fadd_rn(fmaxf(h0 - 2560.0f, 0.0f),
                                          fmaxf(h1 - 2560.0f, 0.0f)),
                                __fadd_rn(fmaxf(h2 - 2560.0f, 0.0f),
                                          fmaxf(h3 - 2560.0f, 0.0f)));
            #pragma unroll
            for (int d = 1; d < 64; d <<= 1) e = __fadd_rn(e, __shfl_xor(e, d));
            float ex = __fmul_rn(e, F(1.0 / 256.0));   // pow2 scale, exact
            float v0 = __fadd_rn(fminf(h0, 2560.0f), ex);
            float v1 = __fadd_rn(fminf(h1, 2560.0f), ex);
            float v2 = __fadd_rn(fminf(h2, 2560.0f), ex);
            float v3 = __fadd_rn(fminf(h3, 2560.0f), ex);
            float s0 = v0;
            float s1 = __fadd_rn(s0, v1);
            float s2 = __fadd_rn(s1, v2);
            float s3 = __fadd_rn(s2, v3);
            float sc = s3;
            #pragma unroll
            for (int d = 1; d < 64; d <<= 1) {
                float u2 = __shfl_up(sc, d);
                if (lane >= d) sc = __fadd_rn(sc, u2);
            }
            float excl = __fsub_rn(sc, s3);   // exact: multiples of 2^-8, <= 2^16
            int lb = trow * 2048 + tcol * 256 + lane * 4;
            float c0 = rintf(__fmul_rn(__fadd_rn(excl, s0), F(255.0 / 65536.0)));
            float c1 = rintf(__fmul_rn(__fadd_rn(excl, s1), F(255.0 / 65536.0)));
            float c2 = rintf(__fmul_rn(__fadd_rn(excl, s2), F(255.0 / 65536.0)));
            float c3 = rintf(__fmul_rn(__fadd_rn(excl, s3), F(255.0 / 65536.0)));
            lutS[lb + 0] = fminf(fmaxf(c0, 0.0f), 255.0f);
            lutS[lb + 1] = fminf(fmaxf(c1, 0.0f), 255.0f);
            lutS[lb + 2] = fminf(fmaxf(c2, 0.0f), 255.0f);
            lutS[lb + 3] = fminf(fmaxf(c3, 0.0f), 255.0f);
        }
    }
    __syncthreads();

    // ---- apply: thread t owns cols [8t, 8t+8), float4 I/O ----
    const int colbase = t * 8;
    const int base = y * WIDTH + colbase;
    float4 ra = *(const float4*)(x + base);
    float4 rb = *(const float4*)(x + base + 4);
    float4 ga = *(const float4*)(x + base + HW);
    float4 gb = *(const float4*)(x + base + HW + 4);
    float4 ba = *(const float4*)(x + base + 2 * HW);
    float4 bb = *(const float4*)(x + base + 2 * HW + 4);

    float4 o_r0, o_r1, o_g0, o_g1, o_b0, o_b1;

#define PIX(RV, GV, BV, J, OR_, OG_, OB_) {                                       \
    int col = colbase + (J);                                                      \
    int l8; float A_, B_;                                                         \
    rgb2lab_px((RV), (GV), (BV), l8, A_, B_);                                     \
    float fxc = fminf(fmaxf(((float)col + 0.5f) * (1.0f / 256.0f) - 0.5f, 0.0f), 7.0f); \
    int x0 = (int)floorf(fxc);                                                    \
    int x1 = min(x0 + 1, 7);                                                      \
    float wx = __fsub_rn(fxc, (float)x0);                                         \
    float omwx = __fsub_rn(1.0f, wx);                                             \
    float g00 = lutS[x0 * 256 + l8];                                              \
    float g01 = lutS[x1 * 256 + l8];                                              \
    float g10 = lutS[2048 + x0 * 256 + l8];                                       \
    float g11 = lutS[2048 + x1 * 256 + l8];                                       \
    float top_ = __fadd_rn(__fmul_rn(omwx, g00), __fmul_rn(wx, g01));             \
    float bot_ = __fadd_rn(__fmul_rn(omwx, g10), __fmul_rn(wx, g11));             \
    float Leq = __fmul_rn(__fadd_rn(__fmul_rn(omwy, top_), __fmul_rn(wy, bot_)),  \
                          F(100.0 / 255.0));                                      \
    lab2rgb_px(Leq, A_, B_, (OR_), (OG_), (OB_));                                 \
}

    PIX(ra.x, ga.x, ba.x, 0, o_r0.x, o_g0.x, o_b0.x);
    PIX(ra.y, ga.y, ba.y, 1, o_r0.y, o_g0.y, o_b0.y);
    PIX(ra.z, ga.z, ba.z, 2, o_r0.z, o_g0.z, o_b0.z);
    PIX(ra.w, ga.w, ba.w, 3, o_r0.w, o_g0.w, o_b0.w);
    PIX(rb.x, gb.x, bb.x, 4, o_r1.x, o_g1.x, o_b1.x);
    PIX(rb.y, gb.y, bb.y, 5, o_r1.y, o_g1.y, o_b1.y);
    PIX(rb.z, gb.z, bb.z, 6, o_r1.z, o_g1.z, o_b1.z);
    PIX(rb.w, gb.w, bb.w, 7, o_r1.w, o_g1.w, o_b1.w);
#undef PIX

    *(float4*)(out + base)              = o_r0;
    *(float4*)(out + base + 4)          = o_r1;
    *(float4*)(out + base + HW)         = o_g0;
    *(float4*)(out + base + HW + 4)     = o_g1;
    *(float4*)(out + base + 2 * HW)     = o_b0;
    *(float4*)(out + base + 2 * HW + 4) = o_b1;
}

extern "C" void kernel_launch(void* const* d_in, const int* in_sizes, int n_in,
                              void* d_out, int out_size, void* d_ws, size_t ws_size,
                              hipStream_t stream) {
    const float* x = (const float*)d_in[0];
    float* out = (float*)d_out;
    unsigned int* hist = (unsigned int*)d_ws;          // 64*256*4 = 64 KiB

    (void)hipMemsetAsync(hist, 0, 65536, stream);
    k_histY<<<2048, 256, 0, stream>>>(x, hist);
    k_lut_apply<<<2048, 256, 0, stream>>>(x, hist, out);
}

// Round 4
// 132.781 us; speedup vs baseline: 1.0683x; 1.0683x over previous
//
#include <hip/hip_runtime.h>
#include <stdint.h>

#define HW 4194304      // 2048*2048
#define WIDTH 2048
#define F(x) ((float)(x))   // double literal -> f32, exactly like numpy scalar promotion

// ---------------------------------------------------------------------------
// Bit-exact replication of glibc sysdeps/ieee754/flt-32/s_cbrtf.c (pre-2.41)
// — what np.cbrt(float32) resolves to on the host. EMPIRICAL RULE (R2/R5/R6
// vs R3): ALL THREE channels (fx, fy, fz) must use this exact path; any
// deviation in fx/fz fails at absmax 2.73e-2 even though the perturbation
// model says it shouldn't. Do not substitute HW transcendentals here.
// ---------------------------------------------------------------------------
__device__ __forceinline__ float cbrtf_glibc(float x) {
    unsigned int bits = __float_as_uint(x);
    int xe = (int)((bits >> 23) & 0xFF) - 126;
    float xm = __uint_as_float((bits & 0x007FFFFFu) | 0x3F000000u);

    static const double factor[5] = {
        1.0 / 1.5874010519681994748,   // 1 / 2^(2/3)
        1.0 / 1.2599210498948731648,   // 1 / 2^(1/3)
        1.0,
        1.2599210498948731648,         // 2^(1/3)
        1.5874010519681994748          // 2^(2/3)
    };

    double xmd = (double)xm;
    double p = __dsub_rn(0.697570460207922770, __dmul_rn(0.191502161678719066, xmd));
    p = __dadd_rn(0.492659620528969547, __dmul_rn(p, xmd));
    float u = (float)p;

    float t2 = __fmul_rn(__fmul_rn(u, u), u);   // float, two roundings (as glibc)

    double ud  = (double)u;
    double t2d = (double)t2;
    double num = __dmul_rn(ud, __dadd_rn(t2d, __dmul_rn(2.0, xmd)));
    double den = __dadd_rn(__dmul_rn(2.0, t2d), xmd);
    double ym  = __dmul_rn(__ddiv_rn(num, den), factor[2 + (xe % 3)]);
    float ymf = (float)ym;

    return ldexpf(ymf, xe / 3);
}

// Exact forward path — the ONLY forward path (see empirical rule above).
__device__ __forceinline__ void rgb2lab_px(float r, float g, float b,
                                           int& l8, float& A_, float& B_) {
    float X = __fadd_rn(__fadd_rn(__fmul_rn(r, F(0.412453)), __fmul_rn(g, F(0.357580))), __fmul_rn(b, F(0.180423)));
    float Y = __fadd_rn(__fadd_rn(__fmul_rn(r, F(0.212671)), __fmul_rn(g, F(0.715160))), __fmul_rn(b, F(0.072169)));
    float Z = __fadd_rn(__fadd_rn(__fmul_rn(r, F(0.019334)), __fmul_rn(g, F(0.119193))), __fmul_rn(b, F(0.950227)));
    X = __fdiv_rn(X, F(0.950456));
    Z = __fdiv_rn(Z, F(1.088754));
    const float EPS = F(0.008856);
    const float C0  = F(16.0 / 116.0);
    float fx = (X > EPS) ? cbrtf_glibc(X) : __fadd_rn(__fmul_rn(F(7.787), X), C0);
    float fy = (Y > EPS) ? cbrtf_glibc(Y) : __fadd_rn(__fmul_rn(F(7.787), Y), C0);
    float fz = (Z > EPS) ? cbrtf_glibc(Z) : __fadd_rn(__fmul_rn(F(7.787), Z), C0);
    float L  = __fsub_rn(__fmul_rn(F(116.0), fy), F(16.0));
    A_ = __fmul_rn(F(500.0), __fsub_rn(fx, fy));
    B_ = __fmul_rn(F(200.0), __fsub_rn(fy, fz));
    float Lr = rintf(__fmul_rn(L, F(255.0 / 100.0)));
    Lr = fminf(fmaxf(Lr, 0.0f), 255.0f);
    l8 = (int)Lr;
}

// lab2rgb epilogue (value-returning).
__device__ __forceinline__ void lab2rgb_px(float Leq, float A_, float B_,
                                           float& rr, float& gg, float& bb) {
    const float EPS = F(0.008856);
    const float C0  = F(16.0 / 116.0);
    float fy2 = __fdiv_rn(__fadd_rn(Leq, 16.0f), 116.0f);
    float fx2 = __fadd_rn(fy2, __fdiv_rn(A_, 500.0f));
    float fz2 = __fsub_rn(fy2, __fdiv_rn(B_, 200.0f));
    float t3;
    t3 = fx2 * fx2 * fx2;
    float X = ((t3 > EPS) ? t3 : __fdiv_rn(__fsub_rn(fx2, C0), F(7.787))) * F(0.950456);
    t3 = fy2 * fy2 * fy2;
    float Y = ((t3 > EPS) ? t3 : __fdiv_rn(__fsub_rn(fy2, C0), F(7.787))) * F(1.0);
    t3 = fz2 * fz2 * fz2;
    float Z = ((t3 > EPS) ? t3 : __fdiv_rn(__fsub_rn(fz2, C0), F(7.787))) * F(1.088754);
    rr = __fadd_rn(__fadd_rn(__fmul_rn(X, F(3.240479)),  __fmul_rn(Y, F(-1.537150))), __fmul_rn(Z, F(-0.498535)));
    gg = __fadd_rn(__fadd_rn(__fmul_rn(X, F(-0.969256)), __fmul_rn(Y, F(1.875992))),  __fmul_rn(Z, F(0.041556)));
    bb = __fadd_rn(__fadd_rn(__fmul_rn(X, F(0.055648)),  __fmul_rn(Y, F(-0.204043))), __fmul_rn(Z, F(1.057311)));
    rr = fminf(fmaxf(rr, 0.0f), 1.0f);
    gg = fminf(fmaxf(gg, 0.0f), 1.0f);
    bb = fminf(fmaxf(bb, 0.0f), 1.0f);
}

// ===========================================================================
// K1: full rgb2lab ONCE per pixel. Thread t owns cols [4t,4t+4) and
// [1024+4t, 1024+4t+4) — every load/store is a per-instruction-coalesced
// float4 (lane l at l*16B contiguous). Stores A-plane / B-plane (SoA) +
// packed l8 (u32 per 4 px). LDS hist + global atomic merge.
// __launch_bounds__(256,8): R3 measured 24-32 VGPR for this code family, so
// the 64-VGPR cap is free — 8 blocks/CU co-resident to hide LDS-atomic and
// HBM latency (R3 ran at only 16 waves/CU).
// ===========================================================================
__global__ __launch_bounds__(256, 8) void k_hist_ab(const float* __restrict__ x,
        unsigned int* __restrict__ hist,
        float* __restrict__ Abuf, float* __restrict__ Bbuf,
        unsigned int* __restrict__ l8buf, int store) {
    __shared__ unsigned int h[2048];
    const int t = threadIdx.x;
    const int y = blockIdx.x;
    #pragma unroll
    for (int i = 0; i < 8; ++i) h[i * 256 + t] = 0;
    __syncthreads();

    const int rowbase = y * WIDTH;
    #pragma unroll
    for (int ch = 0; ch < 2; ++ch) {
        const int col0 = ch * 1024 + 4 * t;
        const int idx  = rowbase + col0;
        float4 r4 = *(const float4*)(x + idx);
        float4 g4 = *(const float4*)(x + idx + HW);
        float4 b4 = *(const float4*)(x + idx + 2 * HW);
        int l80, l81, l82, l83;
        float A0, A1, A2, A3, B0, B1, B2, B3;
        rgb2lab_px(r4.x, g4.x, b4.x, l80, A0, B0);
        rgb2lab_px(r4.y, g4.y, b4.y, l81, A1, B1);
        rgb2lab_px(r4.z, g4.z, b4.z, l82, A2, B2);
        rgb2lab_px(r4.w, g4.w, b4.w, l83, A3, B3);
        const int hb = (col0 >> 8) << 8;   // tile-col uniform over the 4 px
        atomicAdd(&h[hb + l80], 1u);
        atomicAdd(&h[hb + l81], 1u);
        atomicAdd(&h[hb + l82], 1u);
        atomicAdd(&h[hb + l83], 1u);
        if (store) {
            *(float4*)(Abuf + idx) = make_float4(A0, A1, A2, A3);
            *(float4*)(Bbuf + idx) = make_float4(B0, B1, B2, B3);
            l8buf[idx >> 2] = (unsigned)l80 | ((unsigned)l81 << 8)
                            | ((unsigned)l82 << 16) | ((unsigned)l83 << 24);
        }
    }
    __syncthreads();
    unsigned int* gh = hist + (y >> 8) * 2048;
    #pragma unroll
    for (int i = 0; i < 8; ++i) {
        unsigned int v = h[i * 256 + t];
        if (v) atomicAdd(&gh[i * 256 + t], v);
    }
}

// ===========================================================================
// K2: in-block LUT build (wave-scan, BIT-EXACT — validated in R2/R3: all
// partial sums are multiples of 2^-8 bounded by 2^16 => exact in f32 in any
// association => identical to the reference serial cumsum) + apply from the
// STORED A/B/l8 — the 3 glibc-cbrt chains are gone from this kernel, which
// R3 measured as 77%-VALUBusy precisely because of them.
// ===========================================================================
__global__ __launch_bounds__(256, 8) void k_lut_apply(const float* __restrict__ x,
        const unsigned int* __restrict__ hist,
        const float* __restrict__ Abuf, const float* __restrict__ Bbuf,
        const unsigned int* __restrict__ l8buf,
        float* __restrict__ out, int stored) {
    __shared__ float lutS[4096];   // [2][8][256]: tile-row y0, tile-row y1
    const int t = threadIdx.x;
    const int y = blockIdx.x;

    float fyc = fminf(fmaxf(((float)y + 0.5f) * (1.0f / 256.0f) - 0.5f, 0.0f), 7.0f);
    int y0 = (int)floorf(fyc);
    int y1 = min(y0 + 1, 7);
    float wy = __fsub_rn(fyc, (float)y0);
    float omwy = __fsub_rn(1.0f, wy);

    // ---- LUT build: 4 waves x 4 tiles, lane owns 4 bins (verified exact) ----
    {
        const int lane = t & 63;
        const int w = t >> 6;
        #pragma unroll
        for (int i = 0; i < 4; ++i) {
            int gidx = w * 4 + i;             // 0..15
            int trow = gidx >> 3;             // 0 = y0 row, 1 = y1 row
            int tcol = gidx & 7;
            int tile = (trow ? y1 : y0) * 8 + tcol;
            uint4 hv = *(const uint4*)(hist + tile * 256 + lane * 4);
            float h0 = (float)hv.x, h1 = (float)hv.y, h2 = (float)hv.z, h3 = (float)hv.w;
            float e = __fadd_rn(__fadd_rn(fmaxf(h0 - 2560.0f, 0.0f),
                                          fmaxf(h1 - 2560.0f, 0.0f)),
                                __fadd_rn(fmaxf(h2 - 2560.0f, 0.0f),
                                          fmaxf(h3 - 2560.0f, 0.0f)));
            #pragma unroll
            for (int d = 1; d < 64; d <<= 1) e = __fadd_rn(e, __shfl_xor(e, d));
            float ex = __fmul_rn(e, F(1.0 / 256.0));   // pow2 scale, exact
            float v0 = __fadd_rn(fminf(h0, 2560.0f), ex);
            float v1 = __fadd_rn(fminf(h1, 2560.0f), ex);
            float v2 = __fadd_rn(fminf(h2, 2560.0f), ex);
            float v3 = __fadd_rn(fminf(h3, 2560.0f), ex);
            float s0 = v0;
            float s1 = __fadd_rn(s0, v1);
            float s2 = __fadd_rn(s1, v2);
            float s3 = __fadd_rn(s2, v3);
            float sc = s3;
            #pragma unroll
            for (int d = 1; d < 64; d <<= 1) {
                float u2 = __shfl_up(sc, d);
                if (lane >= d) sc = __fadd_rn(sc, u2);
            }
            float excl = __fsub_rn(sc, s3);   // exact: multiples of 2^-8, <= 2^16
            int lb = trow * 2048 + tcol * 256 + lane * 4;
            float c0 = rintf(__fmul_rn(__fadd_rn(excl, s0), F(255.0 / 65536.0)));
            float c1 = rintf(__fmul_rn(__fadd_rn(excl, s1), F(255.0 / 65536.0)));
            float c2 = rintf(__fmul_rn(__fadd_rn(excl, s2), F(255.0 / 65536.0)));
            float c3 = rintf(__fmul_rn(__fadd_rn(excl, s3), F(255.0 / 65536.0)));
            lutS[lb + 0] = fminf(fmaxf(c0, 0.0f), 255.0f);
            lutS[lb + 1] = fminf(fmaxf(c1, 0.0f), 255.0f);
            lutS[lb + 2] = fminf(fmaxf(c2, 0.0f), 255.0f);
            lutS[lb + 3] = fminf(fmaxf(c3, 0.0f), 255.0f);
        }
    }
    __syncthreads();

    const int rowbase = y * WIDTH;
    #pragma unroll
    for (int ch = 0; ch < 2; ++ch) {
        const int col0 = ch * 1024 + 4 * t;
        const int idx  = rowbase + col0;
        float A0, A1, A2, A3, B0, B1, B2, B3;
        int l80, l81, l82, l83;
        if (stored) {
            float4 a4 = *(const float4*)(Abuf + idx);
            float4 b4 = *(const float4*)(Bbuf + idx);
            unsigned p = l8buf[idx >> 2];
            A0 = a4.x; A1 = a4.y; A2 = a4.z; A3 = a4.w;
            B0 = b4.x; B1 = b4.y; B2 = b4.z; B3 = b4.w;
            l80 = (int)(p & 0xFFu); l81 = (int)((p >> 8) & 0xFFu);
            l82 = (int)((p >> 16) & 0xFFu); l83 = (int)((p >> 24) & 0xFFu);
        } else {
            float4 r4 = *(const float4*)(x + idx);
            float4 g4 = *(const float4*)(x + idx + HW);
            float4 b4 = *(const float4*)(x + idx + 2 * HW);
            rgb2lab_px(r4.x, g4.x, b4.x, l80, A0, B0);
            rgb2lab_px(r4.y, g4.y, b4.y, l81, A1, B1);
            rgb2lab_px(r4.z, g4.z, b4.z, l82, A2, B2);
            rgb2lab_px(r4.w, g4.w, b4.w, l83, A3, B3);
        }

        float4 o_r, o_g, o_b;

#define PIX(J, L8V, AV, BV, OR_, OG_, OB_) {                                      \
    int col = col0 + (J);                                                         \
    float fxc = fminf(fmaxf(((float)col + 0.5f) * (1.0f / 256.0f) - 0.5f, 0.0f), 7.0f); \
    int xi0 = (int)floorf(fxc);                                                   \
    int xi1 = min(xi0 + 1, 7);                                                    \
    float wx = __fsub_rn(fxc, (float)xi0);                                        \
    float omwx = __fsub_rn(1.0f, wx);                                             \
    float g00 = lutS[xi0 * 256 + (L8V)];                                          \
    float g01 = lutS[xi1 * 256 + (L8V)];                                          \
    float g10 = lutS[2048 + xi0 * 256 + (L8V)];                                   \
    float g11 = lutS[2048 + xi1 * 256 + (L8V)];                                   \
    float top_ = __fadd_rn(__fmul_rn(omwx, g00), __fmul_rn(wx, g01));             \
    float bot_ = __fadd_rn(__fmul_rn(omwx, g10), __fmul_rn(wx, g11));             \
    float Leq = __fmul_rn(__fadd_rn(__fmul_rn(omwy, top_), __fmul_rn(wy, bot_)),  \
                          F(100.0 / 255.0));                                      \
    lab2rgb_px(Leq, (AV), (BV), (OR_), (OG_), (OB_));                             \
}
        PIX(0, l80, A0, B0, o_r.x, o_g.x, o_b.x);
        PIX(1, l81, A1, B1, o_r.y, o_g.y, o_b.y);
        PIX(2, l82, A2, B2, o_r.z, o_g.z, o_b.z);
        PIX(3, l83, A3, B3, o_r.w, o_g.w, o_b.w);
#undef PIX

        *(float4*)(out + idx)          = o_r;
        *(float4*)(out + idx + HW)     = o_g;
        *(float4*)(out + idx + 2 * HW) = o_b;
    }
}

extern "C" void kernel_launch(void* const* d_in, const int* in_sizes, int n_in,
                              void* d_out, int out_size, void* d_ws, size_t ws_size,
                              hipStream_t stream) {
    const float* x = (const float*)d_in[0];
    float* out = (float*)d_out;
    char* ws = (char*)d_ws;
    unsigned int* hist = (unsigned int*)ws;                 // 64*256*4 = 64 KiB
    const size_t off = 131072;
    float* Abuf = (float*)(ws + off);                       // 16 MiB
    float* Bbuf = (float*)(ws + off + (size_t)HW * 4);      // 16 MiB
    unsigned int* l8buf = (unsigned int*)(ws + off + (size_t)HW * 8); // 4 MiB
    const size_t need = off + (size_t)HW * 9;
    const int store = (ws_size >= need) ? 1 : 0;

    (void)hipMemsetAsync(hist, 0, 65536, stream);
    k_hist_ab<<<2048, 256, 0, stream>>>(x, hist, Abuf, Bbuf, l8buf, store);
    k_lut_apply<<<2048, 256, 0, stream>>>(x, hist, Abuf, Bbuf, l8buf, out, store);
}

// Round 5
// 128.322 us; speedup vs baseline: 1.1054x; 1.0348x over previous
//
#include <hip/hip_runtime.h>
#include <stdint.h>

#define HW 4194304      // 2048*2048
#define WIDTH 2048
#define NBLK 2048
#define F(x) ((float)(x))   // double literal -> f32, exactly like numpy scalar promotion

// ---------------------------------------------------------------------------
// Bit-exact replication of glibc sysdeps/ieee754/flt-32/s_cbrtf.c (pre-2.41)
// — what np.cbrt(float32) resolves to on the host. EMPIRICAL RULE (R2/R5/R6
// vs R3): ALL THREE channels (fx, fy, fz) must use this exact path.
// R5 micro-opts (bit-exact, domain xe in [-6,1] since X,Y,Z in (0.008856,~1]):
//  - factor[2+(xe%3)] per-lane .rodata gather -> branchless f64 select of the
//    SAME constants (kills 3 VMEM gathers/px + vmcnt stalls).
//  - ldexpf(ymf, xe/3) with xe/3 in {-2,-1,0} -> exact pow2 multiply
//    (result >= ~0.098, always normal => no rounding => bit-identical).
// ---------------------------------------------------------------------------
__device__ __forceinline__ float cbrtf_glibc(float x) {
    unsigned int bits = __float_as_uint(x);
    int xe = (int)((bits >> 23) & 0xFF) - 126;
    float xm = __uint_as_float((bits & 0x007FFFFFu) | 0x3F000000u);

    double xmd = (double)xm;
    double p = __dsub_rn(0.697570460207922770, __dmul_rn(0.191502161678719066, xmd));
    p = __dadd_rn(0.492659620528969547, __dmul_rn(p, xmd));
    float u = (float)p;

    float t2 = __fmul_rn(__fmul_rn(u, u), u);   // float, two roundings (as glibc)

    double ud  = (double)u;
    double t2d = (double)t2;
    double num = __dmul_rn(ud, __dadd_rn(t2d, __dmul_rn(2.0, xmd)));
    double den = __dadd_rn(__dmul_rn(2.0, t2d), xmd);

    int idx = 2 + (xe % 3);                     // C trunc semantics, as glibc
    double f = (idx == 2) ? 1.0
             : (idx == 0) ? (1.0 / 1.5874010519681994748)
             : (idx == 1) ? (1.0 / 1.2599210498948731648)
             : (idx == 3) ? 1.2599210498948731648
             :              1.5874010519681994748;
    double ym  = __dmul_rn(__ddiv_rn(num, den), f);
    float ymf = (float)ym;

    int q = xe / 3;                             // in {-2,-1,0} for our domain
    float s = (q == 0) ? 1.0f : ((q == -1) ? 0.5f : 0.25f);
    return __fmul_rn(ymf, s);
}

// Exact forward path — the ONLY forward path (see empirical rule above).
__device__ __forceinline__ void rgb2lab_px(float r, float g, float b,
                                           int& l8, float& A_, float& B_) {
    float X = __fadd_rn(__fadd_rn(__fmul_rn(r, F(0.412453)), __fmul_rn(g, F(0.357580))), __fmul_rn(b, F(0.180423)));
    float Y = __fadd_rn(__fadd_rn(__fmul_rn(r, F(0.212671)), __fmul_rn(g, F(0.715160))), __fmul_rn(b, F(0.072169)));
    float Z = __fadd_rn(__fadd_rn(__fmul_rn(r, F(0.019334)), __fmul_rn(g, F(0.119193))), __fmul_rn(b, F(0.950227)));
    X = __fdiv_rn(X, F(0.950456));
    Z = __fdiv_rn(Z, F(1.088754));
    const float EPS = F(0.008856);
    const float C0  = F(16.0 / 116.0);
    float fx = (X > EPS) ? cbrtf_glibc(X) : __fadd_rn(__fmul_rn(F(7.787), X), C0);
    float fy = (Y > EPS) ? cbrtf_glibc(Y) : __fadd_rn(__fmul_rn(F(7.787), Y), C0);
    float fz = (Z > EPS) ? cbrtf_glibc(Z) : __fadd_rn(__fmul_rn(F(7.787), Z), C0);
    float L  = __fsub_rn(__fmul_rn(F(116.0), fy), F(16.0));
    A_ = __fmul_rn(F(500.0), __fsub_rn(fx, fy));
    B_ = __fmul_rn(F(200.0), __fsub_rn(fy, fz));
    float Lr = rintf(__fmul_rn(L, F(255.0 / 100.0)));
    Lr = fminf(fmaxf(Lr, 0.0f), 255.0f);
    l8 = (int)Lr;
}

// lab2rgb epilogue (value-returning).
__device__ __forceinline__ void lab2rgb_px(float Leq, float A_, float B_,
                                           float& rr, float& gg, float& bb) {
    const float EPS = F(0.008856);
    const float C0  = F(16.0 / 116.0);
    float fy2 = __fdiv_rn(__fadd_rn(Leq, 16.0f), 116.0f);
    float fx2 = __fadd_rn(fy2, __fdiv_rn(A_, 500.0f));
    float fz2 = __fsub_rn(fy2, __fdiv_rn(B_, 200.0f));
    float t3;
    t3 = fx2 * fx2 * fx2;
    float X = ((t3 > EPS) ? t3 : __fdiv_rn(__fsub_rn(fx2, C0), F(7.787))) * F(0.950456);
    t3 = fy2 * fy2 * fy2;
    float Y = ((t3 > EPS) ? t3 : __fdiv_rn(__fsub_rn(fy2, C0), F(7.787))) * F(1.0);
    t3 = fz2 * fz2 * fz2;
    float Z = ((t3 > EPS) ? t3 : __fdiv_rn(__fsub_rn(fz2, C0), F(7.787))) * F(1.088754);
    rr = __fadd_rn(__fadd_rn(__fmul_rn(X, F(3.240479)),  __fmul_rn(Y, F(-1.537150))), __fmul_rn(Z, F(-0.498535)));
    gg = __fadd_rn(__fadd_rn(__fmul_rn(X, F(-0.969256)), __fmul_rn(Y, F(1.875992))),  __fmul_rn(Z, F(0.041556)));
    bb = __fadd_rn(__fadd_rn(__fmul_rn(X, F(0.055648)),  __fmul_rn(Y, F(-0.204043))), __fmul_rn(Z, F(1.057311)));
    rr = fminf(fmaxf(rr, 0.0f), 1.0f);
    gg = fminf(fmaxf(gg, 0.0f), 1.0f);
    bb = fminf(fmaxf(bb, 0.0f), 1.0f);
}

// ---------------------------------------------------------------------------
// LUT build for tile-rows (y0,y1) into lutS[4096] — the R2/R3/R4-verified
// BIT-EXACT wave-scan (all partial sums are multiples of 2^-8 bounded by
// 2^16 => exact in f32 in any association => identical to the reference
// serial cumsum). ATOMIC_LOADS=true forces coherent-point reads (needed when
// the hist was produced in the SAME kernel by other blocks — R2-verified).
// ---------------------------------------------------------------------------
template<bool ATOMIC_LOADS>
__device__ __forceinline__ void build_luts(const unsigned int* __restrict__ hist,
                                           float* lutS, int y0, int y1, int t) {
    const int lane = t & 63;
    const int w = t >> 6;
    #pragma unroll
    for (int i = 0; i < 4; ++i) {
        int gidx = w * 4 + i;             // 0..15
        int trow = gidx >> 3;             // 0 = y0 row, 1 = y1 row
        int tcol = gidx & 7;
        int tile = (trow ? y1 : y0) * 8 + tcol;
        float h0, h1, h2, h3;
        if (ATOMIC_LOADS) {
            const unsigned int* hp = hist + tile * 256 + lane * 4;
            h0 = (float)__hip_atomic_load(&hp[0], __ATOMIC_RELAXED, __HIP_MEMORY_SCOPE_AGENT);
            h1 = (float)__hip_atomic_load(&hp[1], __ATOMIC_RELAXED, __HIP_MEMORY_SCOPE_AGENT);
            h2 = (float)__hip_atomic_load(&hp[2], __ATOMIC_RELAXED, __HIP_MEMORY_SCOPE_AGENT);
            h3 = (float)__hip_atomic_load(&hp[3], __ATOMIC_RELAXED, __HIP_MEMORY_SCOPE_AGENT);
        } else {
            uint4 hv = *(const uint4*)(hist + tile * 256 + lane * 4);
            h0 = (float)hv.x; h1 = (float)hv.y; h2 = (float)hv.z; h3 = (float)hv.w;
        }
        float e = __fadd_rn(__fadd_rn(fmaxf(h0 - 2560.0f, 0.0f),
                                      fmaxf(h1 - 2560.0f, 0.0f)),
                            __fadd_rn(fmaxf(h2 - 2560.0f, 0.0f),
                                      fmaxf(h3 - 2560.0f, 0.0f)));
        #pragma unroll
        for (int d = 1; d < 64; d <<= 1) e = __fadd_rn(e, __shfl_xor(e, d));
        float ex = __fmul_rn(e, F(1.0 / 256.0));   // pow2 scale, exact
        float v0 = __fadd_rn(fminf(h0, 2560.0f), ex);
        float v1 = __fadd_rn(fminf(h1, 2560.0f), ex);
        float v2 = __fadd_rn(fminf(h2, 2560.0f), ex);
        float v3 = __fadd_rn(fminf(h3, 2560.0f), ex);
        float s0 = v0;
        float s1 = __fadd_rn(s0, v1);
        float s2 = __fadd_rn(s1, v2);
        float s3 = __fadd_rn(s2, v3);
        float sc = s3;
        #pragma unroll
        for (int d = 1; d < 64; d <<= 1) {
            float u2 = __shfl_up(sc, d);
            if (lane >= d) sc = __fadd_rn(sc, u2);
        }
        float excl = __fsub_rn(sc, s3);   // exact: multiples of 2^-8, <= 2^16
        int lb = trow * 2048 + tcol * 256 + lane * 4;
        float c0 = rintf(__fmul_rn(__fadd_rn(excl, s0), F(255.0 / 65536.0)));
        float c1 = rintf(__fmul_rn(__fadd_rn(excl, s1), F(255.0 / 65536.0)));
        float c2 = rintf(__fmul_rn(__fadd_rn(excl, s2), F(255.0 / 65536.0)));
        float c3 = rintf(__fmul_rn(__fadd_rn(excl, s3), F(255.0 / 65536.0)));
        lutS[lb + 0] = fminf(fmaxf(c0, 0.0f), 255.0f);
        lutS[lb + 1] = fminf(fmaxf(c1, 0.0f), 255.0f);
        lutS[lb + 2] = fminf(fmaxf(c2, 0.0f), 255.0f);
        lutS[lb + 3] = fminf(fmaxf(c3, 0.0f), 255.0f);
    }
}

// Bilinear interp + lab2rgb + float4 store for 4 px (shared by both paths).
__device__ __forceinline__ void apply4(const float* lutS, int col0, int idx,
        int l80, int l81, int l82, int l83,
        float A0, float A1, float A2, float A3,
        float B0, float B1, float B2, float B3,
        float wy, float omwy, float* __restrict__ out) {
    float4 o_r, o_g, o_b;
#define PIX(J, L8V, AV, BV, OR_, OG_, OB_) {                                      \
    int col = col0 + (J);                                                         \
    float fxc = fminf(fmaxf(((float)col + 0.5f) * (1.0f / 256.0f) - 0.5f, 0.0f), 7.0f); \
    int xi0 = (int)floorf(fxc);                                                   \
    int xi1 = min(xi0 + 1, 7);                                                    \
    float wx = __fsub_rn(fxc, (float)xi0);                                        \
    float omwx = __fsub_rn(1.0f, wx);                                             \
    float g00 = lutS[xi0 * 256 + (L8V)];                                          \
    float g01 = lutS[xi1 * 256 + (L8V)];                                          \
    float g10 = lutS[2048 + xi0 * 256 + (L8V)];                                   \
    float g11 = lutS[2048 + xi1 * 256 + (L8V)];                                   \
    float top_ = __fadd_rn(__fmul_rn(omwx, g00), __fmul_rn(wx, g01));             \
    float bot_ = __fadd_rn(__fmul_rn(omwx, g10), __fmul_rn(wx, g11));             \
    float Leq = __fmul_rn(__fadd_rn(__fmul_rn(omwy, top_), __fmul_rn(wy, bot_)),  \
                          F(100.0 / 255.0));                                      \
    lab2rgb_px(Leq, (AV), (BV), (OR_), (OG_), (OB_));                             \
}
    PIX(0, l80, A0, B0, o_r.x, o_g.x, o_b.x);
    PIX(1, l81, A1, B1, o_r.y, o_g.y, o_b.y);
    PIX(2, l82, A2, B2, o_r.z, o_g.z, o_b.z);
    PIX(3, l83, A3, B3, o_r.w, o_g.w, o_b.w);
#undef PIX
    *(float4*)(out + idx)          = o_r;
    *(float4*)(out + idx + HW)     = o_g;
    *(float4*)(out + idx + 2 * HW) = o_b;
}

// ===========================================================================
// FUSED single kernel, REGULAR launch (graph-capturable). One block per row,
// 2048 blocks, __launch_bounds__(256,8) => 8 blk/CU co-resident (host-checked;
// fallback otherwise). NO register state crosses the wait — A/B/l8 round-trip
// through ws exactly as R4 (each thread reads back its OWN stores => no
// coherence concern, and the data is L2/LLC-hot ~50µs later). Gating is
// per-TILE-ROW (rowdone[8] counters), not a full grid barrier: release-
// increment after the hist merge, acquire-spin until the 2 needed tile-rows
// reach 256 — the R2-correctness-verified agent-scope atomic pattern.
// ===========================================================================
__global__ __launch_bounds__(256, 8) void k_fused(const float* __restrict__ x,
        unsigned int* __restrict__ hist, unsigned int* __restrict__ rowdone,
        float* __restrict__ Abuf, float* __restrict__ Bbuf,
        unsigned int* __restrict__ l8buf, float* __restrict__ out) {
    __shared__ float lutS[4096];   // 16 KB; first 8 KB doubles as u32 hist in phase 1
    unsigned int* h = (unsigned int*)lutS;
    const int t = threadIdx.x;
    const int y = blockIdx.x;

    // ---- phase 1: rgb2lab + LDS hist + stores (R4's k_hist_ab body) ----
    #pragma unroll
    for (int i = 0; i < 8; ++i) h[i * 256 + t] = 0;
    __syncthreads();

    const int rowbase = y * WIDTH;
    #pragma unroll
    for (int ch = 0; ch < 2; ++ch) {
        const int col0 = ch * 1024 + 4 * t;
        const int idx  = rowbase + col0;
        float4 r4 = *(const float4*)(x + idx);
        float4 g4 = *(const float4*)(x + idx + HW);
        float4 b4 = *(const float4*)(x + idx + 2 * HW);
        int l80, l81, l82, l83;
        float A0, A1, A2, A3, B0, B1, B2, B3;
        rgb2lab_px(r4.x, g4.x, b4.x, l80, A0, B0);
        rgb2lab_px(r4.y, g4.y, b4.y, l81, A1, B1);
        rgb2lab_px(r4.z, g4.z, b4.z, l82, A2, B2);
        rgb2lab_px(r4.w, g4.w, b4.w, l83, A3, B3);
        const int hb = (col0 >> 8) << 8;
        atomicAdd(&h[hb + l80], 1u);
        atomicAdd(&h[hb + l81], 1u);
        atomicAdd(&h[hb + l82], 1u);
        atomicAdd(&h[hb + l83], 1u);
        *(float4*)(Abuf + idx) = make_float4(A0, A1, A2, A3);
        *(float4*)(Bbuf + idx) = make_float4(B0, B1, B2, B3);
        l8buf[idx >> 2] = (unsigned)l80 | ((unsigned)l81 << 8)
                        | ((unsigned)l82 << 16) | ((unsigned)l83 << 24);
    }
    __syncthreads();
    {
        unsigned int* gh = hist + (y >> 8) * 2048;
        #pragma unroll
        for (int i = 0; i < 8; ++i) {
            unsigned int v = h[i * 256 + t];
            if (v) atomicAdd(&gh[i * 256 + t], v);
        }
    }
    __syncthreads();

    // ---- tile-row interp params ----
    float fyc = fminf(fmaxf(((float)y + 0.5f) * (1.0f / 256.0f) - 0.5f, 0.0f), 7.0f);
    int y0 = (int)floorf(fyc);
    int y1 = min(y0 + 1, 7);
    float wy = __fsub_rn(fyc, (float)y0);
    float omwy = __fsub_rn(1.0f, wy);

    // ---- signal own tile-row done; wait for the two needed tile-rows ----
    if (t == 0) {
        __threadfence();                                   // release hist atomics
        atomicAdd(&rowdone[y >> 8], 1u);                   // device-scope
        long limit = 1L << 18;                             // bounded (~tens of ms max)
        while (limit-- > 0) {
            unsigned a = __hip_atomic_load(&rowdone[y0], __ATOMIC_ACQUIRE, __HIP_MEMORY_SCOPE_AGENT);
            unsigned b = __hip_atomic_load(&rowdone[y1], __ATOMIC_ACQUIRE, __HIP_MEMORY_SCOPE_AGENT);
            if (a == 256u && b == 256u) break;
            __builtin_amdgcn_s_sleep(2);
        }
    }
    __syncthreads();

    // ---- phase 2: build the 16 LUTs (overwrites the LDS hist copy) ----
    build_luts<true>(hist, lutS, y0, y1, t);
    __syncthreads();

    // ---- phase 3: apply from own stored A/B/l8 ----
    #pragma unroll
    for (int ch = 0; ch < 2; ++ch) {
        const int col0 = ch * 1024 + 4 * t;
        const int idx  = rowbase + col0;
        float4 a4 = *(const float4*)(Abuf + idx);
        float4 b4 = *(const float4*)(Bbuf + idx);
        unsigned p = l8buf[idx >> 2];
        apply4(lutS, col0, idx,
               (int)(p & 0xFFu), (int)((p >> 8) & 0xFFu),
               (int)((p >> 16) & 0xFFu), (int)((p >> 24) & 0xFFu),
               a4.x, a4.y, a4.z, a4.w, b4.x, b4.y, b4.z, b4.w,
               wy, omwy, out);
    }
}

// ===========================================================================
// FALLBACK: R4's verified 2-kernel pipeline (+ the bit-exact cbrt micro-opts).
// ===========================================================================
__global__ __launch_bounds__(256, 8) void k_hist_ab(const float* __restrict__ x,
        unsigned int* __restrict__ hist,
        float* __restrict__ Abuf, float* __restrict__ Bbuf,
        unsigned int* __restrict__ l8buf, int store) {
    __shared__ unsigned int h[2048];
    const int t = threadIdx.x;
    const int y = blockIdx.x;
    #pragma unroll
    for (int i = 0; i < 8; ++i) h[i * 256 + t] = 0;
    __syncthreads();

    const int rowbase = y * WIDTH;
    #pragma unroll
    for (int ch = 0; ch < 2; ++ch) {
        const int col0 = ch * 1024 + 4 * t;
        const int idx  = rowbase + col0;
        float4 r4 = *(const float4*)(x + idx);
        float4 g4 = *(const float4*)(x + idx + HW);
        float4 b4 = *(const float4*)(x + idx + 2 * HW);
        int l80, l81, l82, l83;
        float A0, A1, A2, A3, B0, B1, B2, B3;
        rgb2lab_px(r4.x, g4.x, b4.x, l80, A0, B0);
        rgb2lab_px(r4.y, g4.y, b4.y, l81, A1, B1);
        rgb2lab_px(r4.z, g4.z, b4.z, l82, A2, B2);
        rgb2lab_px(r4.w, g4.w, b4.w, l83, A3, B3);
        const int hb = (col0 >> 8) << 8;
        atomicAdd(&h[hb + l80], 1u);
        atomicAdd(&h[hb + l81], 1u);
        atomicAdd(&h[hb + l82], 1u);
        atomicAdd(&h[hb + l83], 1u);
        if (store) {
            *(float4*)(Abuf + idx) = make_float4(A0, A1, A2, A3);
            *(float4*)(Bbuf + idx) = make_float4(B0, B1, B2, B3);
            l8buf[idx >> 2] = (unsigned)l80 | ((unsigned)l81 << 8)
                            | ((unsigned)l82 << 16) | ((unsigned)l83 << 24);
        }
    }
    __syncthreads();
    unsigned int* gh = hist + (y >> 8) * 2048;
    #pragma unroll
    for (int i = 0; i < 8; ++i) {
        unsigned int v = h[i * 256 + t];
        if (v) atomicAdd(&gh[i * 256 + t], v);
    }
}

__global__ __launch_bounds__(256, 8) void k_lut_apply(const float* __restrict__ x,
        const unsigned int* __restrict__ hist,
        const float* __restrict__ Abuf, const float* __restrict__ Bbuf,
        const unsigned int* __restrict__ l8buf,
        float* __restrict__ out, int stored) {
    __shared__ float lutS[4096];
    const int t = threadIdx.x;
    const int y = blockIdx.x;

    float fyc = fminf(fmaxf(((float)y + 0.5f) * (1.0f / 256.0f) - 0.5f, 0.0f), 7.0f);
    int y0 = (int)floorf(fyc);
    int y1 = min(y0 + 1, 7);
    float wy = __fsub_rn(fyc, (float)y0);
    float omwy = __fsub_rn(1.0f, wy);

    build_luts<false>(hist, lutS, y0, y1, t);
    __syncthreads();

    const int rowbase = y * WIDTH;
    #pragma unroll
    for (int ch = 0; ch < 2; ++ch) {
        const int col0 = ch * 1024 + 4 * t;
        const int idx  = rowbase + col0;
        float A0, A1, A2, A3, B0, B1, B2, B3;
        int l80, l81, l82, l83;
        if (stored) {
            float4 a4 = *(const float4*)(Abuf + idx);
            float4 b4 = *(const float4*)(Bbuf + idx);
            unsigned p = l8buf[idx >> 2];
            A0 = a4.x; A1 = a4.y; A2 = a4.z; A3 = a4.w;
            B0 = b4.x; B1 = b4.y; B2 = b4.z; B3 = b4.w;
            l80 = (int)(p & 0xFFu); l81 = (int)((p >> 8) & 0xFFu);
            l82 = (int)((p >> 16) & 0xFFu); l83 = (int)((p >> 24) & 0xFFu);
        } else {
            float4 r4 = *(const float4*)(x + idx);
            float4 g4 = *(const float4*)(x + idx + HW);
            float4 b4 = *(const float4*)(x + idx + 2 * HW);
            rgb2lab_px(r4.x, g4.x, b4.x, l80, A0, B0);
            rgb2lab_px(r4.y, g4.y, b4.y, l81, A1, B1);
            rgb2lab_px(r4.z, g4.z, b4.z, l82, A2, B2);
            rgb2lab_px(r4.w, g4.w, b4.w, l83, A3, B3);
        }
        apply4(lutS, col0, idx, l80, l81, l82, l83,
               A0, A1, A2, A3, B0, B1, B2, B3, wy, omwy, out);
    }
}

extern "C" void kernel_launch(void* const* d_in, const int* in_sizes, int n_in,
                              void* d_out, int out_size, void* d_ws, size_t ws_size,
                              hipStream_t stream) {
    const float* x = (const float*)d_in[0];
    float* out = (float*)d_out;
    char* ws = (char*)d_ws;
    unsigned int* hist = (unsigned int*)ws;                 // 64 KiB
    unsigned int* rowdone = (unsigned int*)(ws + 65536);    // 8 x u32
    const size_t off = 131072;
    float* Abuf = (float*)(ws + off);                       // 16 MiB
    float* Bbuf = (float*)(ws + off + (size_t)HW * 4);      // 16 MiB
    unsigned int* l8buf = (unsigned int*)(ws + off + (size_t)HW * 8); // 4 MiB
    const size_t need = off + (size_t)HW * 9;
    const int store = (ws_size >= need) ? 1 : 0;

    // Host-side co-residency check for the fused kernel (8 blk/CU x 256 CU).
    static int fused_ok = -1;
    if (fused_ok < 0) {
        int nb = 0, ncu = 0, dev = 0;
        (void)hipGetDevice(&dev);
        hipError_t e1 = hipOccupancyMaxActiveBlocksPerMultiprocessor(&nb, k_fused, 256, 0);
        hipError_t e2 = hipDeviceGetAttribute(&ncu, hipDeviceAttributeMultiprocessorCount, dev);
        fused_ok = (e1 == hipSuccess && e2 == hipSuccess && nb * ncu >= NBLK) ? 1 : 0;
    }

    (void)hipMemsetAsync(ws, 0, 65536 + 64, stream);   // hist + rowdone

    if (fused_ok == 1 && store == 1) {
        k_fused<<<NBLK, 256, 0, stream>>>(x, hist, rowdone, Abuf, Bbuf, l8buf, out);
    } else {
        k_hist_ab<<<NBLK, 256, 0, stream>>>(x, hist, Abuf, Bbuf, l8buf, store);
        k_lut_apply<<<NBLK, 256, 0, stream>>>(x, hist, Abuf, Bbuf, l8buf, out, store);
    }
}

// Round 6
// 128.292 us; speedup vs baseline: 1.1057x; 1.0002x over previous
//
#include <hip/hip_runtime.h>
#include <stdint.h>

#define HW 4194304      // 2048*2048
#define WIDTH 2048
#define NBLK 2048
#define F(x) ((float)(x))   // double literal -> f32, exactly like numpy scalar promotion

// ---------------------------------------------------------------------------
// Bit-exact replication of glibc sysdeps/ieee754/flt-32/s_cbrtf.c (pre-2.41)
// — what np.cbrt(float32) resolves to on the host. EMPIRICAL RULE: ALL THREE
// channels (fx, fy, fz) must use this exact path. R5 micro-opts (bit-exact,
// domain xe in [-6,1] since X,Y,Z in (0.008856,~1.09]): branchless f64 factor
// select (no .rodata gather) + exact pow2 multiply instead of ldexpf.
// Validated: absmax unchanged (0.01171875) in R5.
// ---------------------------------------------------------------------------
__device__ __forceinline__ float cbrtf_glibc(float x) {
    unsigned int bits = __float_as_uint(x);
    int xe = (int)((bits >> 23) & 0xFF) - 126;
    float xm = __uint_as_float((bits & 0x007FFFFFu) | 0x3F000000u);

    double xmd = (double)xm;
    double p = __dsub_rn(0.697570460207922770, __dmul_rn(0.191502161678719066, xmd));
    p = __dadd_rn(0.492659620528969547, __dmul_rn(p, xmd));
    float u = (float)p;

    float t2 = __fmul_rn(__fmul_rn(u, u), u);   // float, two roundings (as glibc)

    double ud  = (double)u;
    double t2d = (double)t2;
    double num = __dmul_rn(ud, __dadd_rn(t2d, __dmul_rn(2.0, xmd)));
    double den = __dadd_rn(__dmul_rn(2.0, t2d), xmd);

    int idx = 2 + (xe % 3);                     // C trunc semantics, as glibc
    double f = (idx == 2) ? 1.0
             : (idx == 0) ? (1.0 / 1.5874010519681994748)
             : (idx == 1) ? (1.0 / 1.2599210498948731648)
             : (idx == 3) ? 1.2599210498948731648
             :              1.5874010519681994748;
    double ym  = __dmul_rn(__ddiv_rn(num, den), f);
    float ymf = (float)ym;

    int q = xe / 3;                             // in {-2,-1,0} for our domain
    float s = (q == 0) ? 1.0f : ((q == -1) ? 0.5f : 0.25f);
    return __fmul_rn(ymf, s);
}

// Exact forward path — the ONLY forward path (see empirical rule above).
__device__ __forceinline__ void rgb2lab_px(float r, float g, float b,
                                           int& l8, float& A_, float& B_) {
    float X = __fadd_rn(__fadd_rn(__fmul_rn(r, F(0.412453)), __fmul_rn(g, F(0.357580))), __fmul_rn(b, F(0.180423)));
    float Y = __fadd_rn(__fadd_rn(__fmul_rn(r, F(0.212671)), __fmul_rn(g, F(0.715160))), __fmul_rn(b, F(0.072169)));
    float Z = __fadd_rn(__fadd_rn(__fmul_rn(r, F(0.019334)), __fmul_rn(g, F(0.119193))), __fmul_rn(b, F(0.950227)));
    X = __fdiv_rn(X, F(0.950456));
    Z = __fdiv_rn(Z, F(1.088754));
    const float EPS = F(0.008856);
    const float C0  = F(16.0 / 116.0);
    float fx = (X > EPS) ? cbrtf_glibc(X) : __fadd_rn(__fmul_rn(F(7.787), X), C0);
    float fy = (Y > EPS) ? cbrtf_glibc(Y) : __fadd_rn(__fmul_rn(F(7.787), Y), C0);
    float fz = (Z > EPS) ? cbrtf_glibc(Z) : __fadd_rn(__fmul_rn(F(7.787), Z), C0);
    float L  = __fsub_rn(__fmul_rn(F(116.0), fy), F(16.0));
    A_ = __fmul_rn(F(500.0), __fsub_rn(fx, fy));
    B_ = __fmul_rn(F(200.0), __fsub_rn(fy, fz));
    float Lr = rintf(__fmul_rn(L, F(255.0 / 100.0)));
    Lr = fminf(fmaxf(Lr, 0.0f), 255.0f);
    l8 = (int)Lr;
}

// lab2rgb epilogue (value-returning).
__device__ __forceinline__ void lab2rgb_px(float Leq, float A_, float B_,
                                           float& rr, float& gg, float& bb) {
    const float EPS = F(0.008856);
    const float C0  = F(16.0 / 116.0);
    float fy2 = __fdiv_rn(__fadd_rn(Leq, 16.0f), 116.0f);
    float fx2 = __fadd_rn(fy2, __fdiv_rn(A_, 500.0f));
    float fz2 = __fsub_rn(fy2, __fdiv_rn(B_, 200.0f));
    float t3;
    t3 = fx2 * fx2 * fx2;
    float X = ((t3 > EPS) ? t3 : __fdiv_rn(__fsub_rn(fx2, C0), F(7.787))) * F(0.950456);
    t3 = fy2 * fy2 * fy2;
    float Y = ((t3 > EPS) ? t3 : __fdiv_rn(__fsub_rn(fy2, C0), F(7.787))) * F(1.0);
    t3 = fz2 * fz2 * fz2;
    float Z = ((t3 > EPS) ? t3 : __fdiv_rn(__fsub_rn(fz2, C0), F(7.787))) * F(1.088754);
    rr = __fadd_rn(__fadd_rn(__fmul_rn(X, F(3.240479)),  __fmul_rn(Y, F(-1.537150))), __fmul_rn(Z, F(-0.498535)));
    gg = __fadd_rn(__fadd_rn(__fmul_rn(X, F(-0.969256)), __fmul_rn(Y, F(1.875992))),  __fmul_rn(Z, F(0.041556)));
    bb = __fadd_rn(__fadd_rn(__fmul_rn(X, F(0.055648)),  __fmul_rn(Y, F(-0.204043))), __fmul_rn(Z, F(1.057311)));
    rr = fminf(fmaxf(rr, 0.0f), 1.0f);
    gg = fminf(fmaxf(gg, 0.0f), 1.0f);
    bb = fminf(fmaxf(bb, 0.0f), 1.0f);
}

// ---------------------------------------------------------------------------
// LUT build for tile-rows (y0,y1) into lutS[4096] — the R2..R5-verified
// BIT-EXACT wave-scan (all partial sums multiples of 2^-8, bounded by 2^16 =>
// exact in f32 in any association => identical to reference serial cumsum).
// ---------------------------------------------------------------------------
template<bool ATOMIC_LOADS>
__device__ __forceinline__ void build_luts(const unsigned int* __restrict__ hist,
                                           float* lutS, int y0, int y1, int t) {
    const int lane = t & 63;
    const int w = t >> 6;
    #pragma unroll
    for (int i = 0; i < 4; ++i) {
        int gidx = w * 4 + i;             // 0..15
        int trow = gidx >> 3;             // 0 = y0 row, 1 = y1 row
        int tcol = gidx & 7;
        int tile = (trow ? y1 : y0) * 8 + tcol;
        float h0, h1, h2, h3;
        if (ATOMIC_LOADS) {
            const unsigned int* hp = hist + tile * 256 + lane * 4;
            h0 = (float)__hip_atomic_load(&hp[0], __ATOMIC_RELAXED, __HIP_MEMORY_SCOPE_AGENT);
            h1 = (float)__hip_atomic_load(&hp[1], __ATOMIC_RELAXED, __HIP_MEMORY_SCOPE_AGENT);
            h2 = (float)__hip_atomic_load(&hp[2], __ATOMIC_RELAXED, __HIP_MEMORY_SCOPE_AGENT);
            h3 = (float)__hip_atomic_load(&hp[3], __ATOMIC_RELAXED, __HIP_MEMORY_SCOPE_AGENT);
        } else {
            uint4 hv = *(const uint4*)(hist + tile * 256 + lane * 4);
            h0 = (float)hv.x; h1 = (float)hv.y; h2 = (float)hv.z; h3 = (float)hv.w;
        }
        float e = __fadd_rn(__fadd_rn(fmaxf(h0 - 2560.0f, 0.0f),
                                      fmaxf(h1 - 2560.0f, 0.0f)),
                            __fadd_rn(fmaxf(h2 - 2560.0f, 0.0f),
                                      fmaxf(h3 - 2560.0f, 0.0f)));
        #pragma unroll
        for (int d = 1; d < 64; d <<= 1) e = __fadd_rn(e, __shfl_xor(e, d));
        float ex = __fmul_rn(e, F(1.0 / 256.0));   // pow2 scale, exact
        float v0 = __fadd_rn(fminf(h0, 2560.0f), ex);
        float v1 = __fadd_rn(fminf(h1, 2560.0f), ex);
        float v2 = __fadd_rn(fminf(h2, 2560.0f), ex);
        float v3 = __fadd_rn(fminf(h3, 2560.0f), ex);
        float s0 = v0;
        float s1 = __fadd_rn(s0, v1);
        float s2 = __fadd_rn(s1, v2);
        float s3 = __fadd_rn(s2, v3);
        float sc = s3;
        #pragma unroll
        for (int d = 1; d < 64; d <<= 1) {
            float u2 = __shfl_up(sc, d);
            if (lane >= d) sc = __fadd_rn(sc, u2);
        }
        float excl = __fsub_rn(sc, s3);   // exact: multiples of 2^-8, <= 2^16
        int lb = trow * 2048 + tcol * 256 + lane * 4;
        float c0 = rintf(__fmul_rn(__fadd_rn(excl, s0), F(255.0 / 65536.0)));
        float c1 = rintf(__fmul_rn(__fadd_rn(excl, s1), F(255.0 / 65536.0)));
        float c2 = rintf(__fmul_rn(__fadd_rn(excl, s2), F(255.0 / 65536.0)));
        float c3 = rintf(__fmul_rn(__fadd_rn(excl, s3), F(255.0 / 65536.0)));
        lutS[lb + 0] = fminf(fmaxf(c0, 0.0f), 255.0f);
        lutS[lb + 1] = fminf(fmaxf(c1, 0.0f), 255.0f);
        lutS[lb + 2] = fminf(fmaxf(c2, 0.0f), 255.0f);
        lutS[lb + 3] = fminf(fmaxf(c3, 0.0f), 255.0f);
    }
}

// Bilinear interp + lab2rgb + float4 store for 4 px.
__device__ __forceinline__ void apply4(const float* lutS, int col0, int idx,
        int l80, int l81, int l82, int l83,
        float A0, float A1, float A2, float A3,
        float B0, float B1, float B2, float B3,
        float wy, float omwy, float* __restrict__ out) {
    float4 o_r, o_g, o_b;
#define PIX(J, L8V, AV, BV, OR_, OG_, OB_) {                                      \
    int col = col0 + (J);                                                         \
    float fxc = fminf(fmaxf(((float)col + 0.5f) * (1.0f / 256.0f) - 0.5f, 0.0f), 7.0f); \
    int xi0 = (int)floorf(fxc);                                                   \
    int xi1 = min(xi0 + 1, 7);                                                    \
    float wx = __fsub_rn(fxc, (float)xi0);                                        \
    float omwx = __fsub_rn(1.0f, wx);                                             \
    float g00 = lutS[xi0 * 256 + (L8V)];                                          \
    float g01 = lutS[xi1 * 256 + (L8V)];                                          \
    float g10 = lutS[2048 + xi0 * 256 + (L8V)];                                   \
    float g11 = lutS[2048 + xi1 * 256 + (L8V)];                                   \
    float top_ = __fadd_rn(__fmul_rn(omwx, g00), __fmul_rn(wx, g01));             \
    float bot_ = __fadd_rn(__fmul_rn(omwx, g10), __fmul_rn(wx, g11));             \
    float Leq = __fmul_rn(__fadd_rn(__fmul_rn(omwy, top_), __fmul_rn(wy, bot_)),  \
                          F(100.0 / 255.0));                                      \
    lab2rgb_px(Leq, (AV), (BV), (OR_), (OG_), (OB_));                             \
}
    PIX(0, l80, A0, B0, o_r.x, o_g.x, o_b.x);
    PIX(1, l81, A1, B1, o_r.y, o_g.y, o_b.y);
    PIX(2, l82, A2, B2, o_r.z, o_g.z, o_b.z);
    PIX(3, l83, A3, B3, o_r.w, o_g.w, o_b.w);
#undef PIX
    *(float4*)(out + idx)          = o_r;
    *(float4*)(out + idx + HW)     = o_g;
    *(float4*)(out + idx + 2 * HW) = o_b;
}

// ===========================================================================
// R6 FUSED, REGISTER-STATE variant. Identical sync structure to R5 (verified
// correct + fastest so far), but A/B/l8 live in NAMED SCALAR registers across
// the wait (no arrays — rule #20; R2's spill used arrays). State = 16 f32 +
// 2 u32 = 18 VGPR on top of R5's measured 28 => ~46-50, under the 64 cap of
// __launch_bounds__(256,8). The 37.7 MB ws write + re-read of R5 vanishes.
// Runtime gates: occupancy (all 2048 blocks co-resident) AND
// hipFuncGetAttributes.localSizeBytes == 0 (no spill) — else fall back.
// ===========================================================================
__global__ __launch_bounds__(256, 8) void k_fused_reg(const float* __restrict__ x,
        unsigned int* __restrict__ hist, unsigned int* __restrict__ rowdone,
        float* __restrict__ out) {
    __shared__ float lutS[4096];   // 16 KB; first 8 KB doubles as u32 hist in phase 1
    unsigned int* h = (unsigned int*)lutS;
    const int t = threadIdx.x;
    const int y = blockIdx.x;

    #pragma unroll
    for (int i = 0; i < 8; ++i) h[i * 256 + t] = 0;
    __syncthreads();

    const int rowbase = y * WIDTH;

    // ---- phase 1: rgb2lab, LDS hist; state in named scalars ----
    float A0, A1, A2, A3, A4, A5, A6, A7;
    float B0, B1, B2, B3, B4, B5, B6, B7;
    unsigned pk0, pk1;
    {
        const int col0 = 4 * t;
        const int idx  = rowbase + col0;
        float4 r4 = *(const float4*)(x + idx);
        float4 g4 = *(const float4*)(x + idx + HW);
        float4 b4 = *(const float4*)(x + idx + 2 * HW);
        int l0, l1, l2, l3;
        rgb2lab_px(r4.x, g4.x, b4.x, l0, A0, B0);
        rgb2lab_px(r4.y, g4.y, b4.y, l1, A1, B1);
        rgb2lab_px(r4.z, g4.z, b4.z, l2, A2, B2);
        rgb2lab_px(r4.w, g4.w, b4.w, l3, A3, B3);
        const int hb = (col0 >> 8) << 8;
        atomicAdd(&h[hb + l0], 1u);
        atomicAdd(&h[hb + l1], 1u);
        atomicAdd(&h[hb + l2], 1u);
        atomicAdd(&h[hb + l3], 1u);
        pk0 = (unsigned)l0 | ((unsigned)l1 << 8) | ((unsigned)l2 << 16) | ((unsigned)l3 << 24);
    }
    {
        const int col0 = 1024 + 4 * t;
        const int idx  = rowbase + col0;
        float4 r4 = *(const float4*)(x + idx);
        float4 g4 = *(const float4*)(x + idx + HW);
        float4 b4 = *(const float4*)(x + idx + 2 * HW);
        int l0, l1, l2, l3;
        rgb2lab_px(r4.x, g4.x, b4.x, l0, A4, B4);
        rgb2lab_px(r4.y, g4.y, b4.y, l1, A5, B5);
        rgb2lab_px(r4.z, g4.z, b4.z, l2, A6, B6);
        rgb2lab_px(r4.w, g4.w, b4.w, l3, A7, B7);
        const int hb = (col0 >> 8) << 8;
        atomicAdd(&h[hb + l0], 1u);
        atomicAdd(&h[hb + l1], 1u);
        atomicAdd(&h[hb + l2], 1u);
        atomicAdd(&h[hb + l3], 1u);
        pk1 = (unsigned)l0 | ((unsigned)l1 << 8) | ((unsigned)l2 << 16) | ((unsigned)l3 << 24);
    }
    __syncthreads();
    {
        unsigned int* gh = hist + (y >> 8) * 2048;
        #pragma unroll
        for (int i = 0; i < 8; ++i) {
            unsigned int v = h[i * 256 + t];
            if (v) atomicAdd(&gh[i * 256 + t], v);
        }
    }
    __syncthreads();

    // ---- tile-row interp params ----
    float fyc = fminf(fmaxf(((float)y + 0.5f) * (1.0f / 256.0f) - 0.5f, 0.0f), 7.0f);
    int y0 = (int)floorf(fyc);
    int y1 = min(y0 + 1, 7);
    float wy = __fsub_rn(fyc, (float)y0);
    float omwy = __fsub_rn(1.0f, wy);

    // ---- signal + wait (R5-verified pattern) ----
    if (t == 0) {
        __threadfence();                                   // release hist atomics
        atomicAdd(&rowdone[y >> 8], 1u);                   // device-scope
        long limit = 1L << 18;                             // bounded
        while (limit-- > 0) {
            unsigned a = __hip_atomic_load(&rowdone[y0], __ATOMIC_ACQUIRE, __HIP_MEMORY_SCOPE_AGENT);
            unsigned b = __hip_atomic_load(&rowdone[y1], __ATOMIC_ACQUIRE, __HIP_MEMORY_SCOPE_AGENT);
            if (a == 256u && b == 256u) break;
            __builtin_amdgcn_s_sleep(2);
        }
    }
    __syncthreads();

    // ---- phase 2: build the 16 LUTs (overwrites the LDS hist copy) ----
    build_luts<true>(hist, lutS, y0, y1, t);
    __syncthreads();

    // ---- phase 3: apply straight from registers ----
    apply4(lutS, 4 * t, rowbase + 4 * t,
           (int)(pk0 & 0xFFu), (int)((pk0 >> 8) & 0xFFu),
           (int)((pk0 >> 16) & 0xFFu), (int)((pk0 >> 24) & 0xFFu),
           A0, A1, A2, A3, B0, B1, B2, B3, wy, omwy, out);
    apply4(lutS, 1024 + 4 * t, rowbase + 1024 + 4 * t,
           (int)(pk1 & 0xFFu), (int)((pk1 >> 8) & 0xFFu),
           (int)((pk1 >> 16) & 0xFFu), (int)((pk1 >> 24) & 0xFFu),
           A4, A5, A6, A7, B4, B5, B6, B7, wy, omwy, out);
}

// ===========================================================================
// Fallback A (R5's verified fused, ws round-trip) — used if k_fused_reg
// spills. Fallback B (two-kernel) — used if co-residency fails.
// ===========================================================================
__global__ __launch_bounds__(256, 8) void k_fused_ws(const float* __restrict__ x,
        unsigned int* __restrict__ hist, unsigned int* __restrict__ rowdone,
        float* __restrict__ Abuf, float* __restrict__ Bbuf,
        unsigned int* __restrict__ l8buf, float* __restrict__ out) {
    __shared__ float lutS[4096];
    unsigned int* h = (unsigned int*)lutS;
    const int t = threadIdx.x;
    const int y = blockIdx.x;

    #pragma unroll
    for (int i = 0; i < 8; ++i) h[i * 256 + t] = 0;
    __syncthreads();

    const int rowbase = y * WIDTH;
    #pragma unroll
    for (int ch = 0; ch < 2; ++ch) {
        const int col0 = ch * 1024 + 4 * t;
        const int idx  = rowbase + col0;
        float4 r4 = *(const float4*)(x + idx);
        float4 g4 = *(const float4*)(x + idx + HW);
        float4 b4 = *(const float4*)(x + idx + 2 * HW);
        int l80, l81, l82, l83;
        float A0, A1, A2, A3, B0, B1, B2, B3;
        rgb2lab_px(r4.x, g4.x, b4.x, l80, A0, B0);
        rgb2lab_px(r4.y, g4.y, b4.y, l81, A1, B1);
        rgb2lab_px(r4.z, g4.z, b4.z, l82, A2, B2);
        rgb2lab_px(r4.w, g4.w, b4.w, l83, A3, B3);
        const int hb = (col0 >> 8) << 8;
        atomicAdd(&h[hb + l80], 1u);
        atomicAdd(&h[hb + l81], 1u);
        atomicAdd(&h[hb + l82], 1u);
        atomicAdd(&h[hb + l83], 1u);
        *(float4*)(Abuf + idx) = make_float4(A0, A1, A2, A3);
        *(float4*)(Bbuf + idx) = make_float4(B0, B1, B2, B3);
        l8buf[idx >> 2] = (unsigned)l80 | ((unsigned)l81 << 8)
                        | ((unsigned)l82 << 16) | ((unsigned)l83 << 24);
    }
    __syncthreads();
    {
        unsigned int* gh = hist + (y >> 8) * 2048;
        #pragma unroll
        for (int i = 0; i < 8; ++i) {
            unsigned int v = h[i * 256 + t];
            if (v) atomicAdd(&gh[i * 256 + t], v);
        }
    }
    __syncthreads();

    float fyc = fminf(fmaxf(((float)y + 0.5f) * (1.0f / 256.0f) - 0.5f, 0.0f), 7.0f);
    int y0 = (int)floorf(fyc);
    int y1 = min(y0 + 1, 7);
    float wy = __fsub_rn(fyc, (float)y0);
    float omwy = __fsub_rn(1.0f, wy);

    if (t == 0) {
        __threadfence();
        atomicAdd(&rowdone[y >> 8], 1u);
        long limit = 1L << 18;
        while (limit-- > 0) {
            unsigned a = __hip_atomic_load(&rowdone[y0], __ATOMIC_ACQUIRE, __HIP_MEMORY_SCOPE_AGENT);
            unsigned b = __hip_atomic_load(&rowdone[y1], __ATOMIC_ACQUIRE, __HIP_MEMORY_SCOPE_AGENT);
            if (a == 256u && b == 256u) break;
            __builtin_amdgcn_s_sleep(2);
        }
    }
    __syncthreads();

    build_luts<true>(hist, lutS, y0, y1, t);
    __syncthreads();

    #pragma unroll
    for (int ch = 0; ch < 2; ++ch) {
        const int col0 = ch * 1024 + 4 * t;
        const int idx  = rowbase + col0;
        float4 a4 = *(const float4*)(Abuf + idx);
        float4 b4 = *(const float4*)(Bbuf + idx);
        unsigned p = l8buf[idx >> 2];
        apply4(lutS, col0, idx,
               (int)(p & 0xFFu), (int)((p >> 8) & 0xFFu),
               (int)((p >> 16) & 0xFFu), (int)((p >> 24) & 0xFFu),
               a4.x, a4.y, a4.z, a4.w, b4.x, b4.y, b4.z, b4.w,
               wy, omwy, out);
    }
}

__global__ __launch_bounds__(256, 8) void k_hist_ab(const float* __restrict__ x,
        unsigned int* __restrict__ hist,
        float* __restrict__ Abuf, float* __restrict__ Bbuf,
        unsigned int* __restrict__ l8buf, int store) {
    __shared__ unsigned int h[2048];
    const int t = threadIdx.x;
    const int y = blockIdx.x;
    #pragma unroll
    for (int i = 0; i < 8; ++i) h[i * 256 + t] = 0;
    __syncthreads();

    const int rowbase = y * WIDTH;
    #pragma unroll
    for (int ch = 0; ch < 2; ++ch) {
        const int col0 = ch * 1024 + 4 * t;
        const int idx  = rowbase + col0;
        float4 r4 = *(const float4*)(x + idx);
        float4 g4 = *(const float4*)(x + idx + HW);
        float4 b4 = *(const float4*)(x + idx + 2 * HW);
        int l80, l81, l82, l83;
        float A0, A1, A2, A3, B0, B1, B2, B3;
        rgb2lab_px(r4.x, g4.x, b4.x, l80, A0, B0);
        rgb2lab_px(r4.y, g4.y, b4.y, l81, A1, B1);
        rgb2lab_px(r4.z, g4.z, b4.z, l82, A2, B2);
        rgb2lab_px(r4.w, g4.w, b4.w, l83, A3, B3);
        const int hb = (col0 >> 8) << 8;
        atomicAdd(&h[hb + l80], 1u);
        atomicAdd(&h[hb + l81], 1u);
        atomicAdd(&h[hb + l82], 1u);
        atomicAdd(&h[hb + l83], 1u);
        if (store) {
            *(float4*)(Abuf + idx) = make_float4(A0, A1, A2, A3);
            *(float4*)(Bbuf + idx) = make_float4(B0, B1, B2, B3);
            l8buf[idx >> 2] = (unsigned)l80 | ((unsigned)l81 << 8)
                            | ((unsigned)l82 << 16) | ((unsigned)l83 << 24);
        }
    }
    __syncthreads();
    unsigned int* gh = hist + (y >> 8) * 2048;
    #pragma unroll
    for (int i = 0; i < 8; ++i) {
        unsigned int v = h[i * 256 + t];
        if (v) atomicAdd(&gh[i * 256 + t], v);
    }
}

__global__ __launch_bounds__(256, 8) void k_lut_apply(const float* __restrict__ x,
        const unsigned int* __restrict__ hist,
        const float* __restrict__ Abuf, const float* __restrict__ Bbuf,
        const unsigned int* __restrict__ l8buf,
        float* __restrict__ out, int stored) {
    __shared__ float lutS[4096];
    const int t = threadIdx.x;
    const int y = blockIdx.x;

    float fyc = fminf(fmaxf(((float)y + 0.5f) * (1.0f / 256.0f) - 0.5f, 0.0f), 7.0f);
    int y0 = (int)floorf(fyc);
    int y1 = min(y0 + 1, 7);
    float wy = __fsub_rn(fyc, (float)y0);
    float omwy = __fsub_rn(1.0f, wy);

    build_luts<false>(hist, lutS, y0, y1, t);
    __syncthreads();

    const int rowbase = y * WIDTH;
    #pragma unroll
    for (int ch = 0; ch < 2; ++ch) {
        const int col0 = ch * 1024 + 4 * t;
        const int idx  = rowbase + col0;
        float A0, A1, A2, A3, B0, B1, B2, B3;
        int l80, l81, l82, l83;
        if (stored) {
            float4 a4 = *(const float4*)(Abuf + idx);
            float4 b4 = *(const float4*)(Bbuf + idx);
            unsigned p = l8buf[idx >> 2];
            A0 = a4.x; A1 = a4.y; A2 = a4.z; A3 = a4.w;
            B0 = b4.x; B1 = b4.y; B2 = b4.z; B3 = b4.w;
            l80 = (int)(p & 0xFFu); l81 = (int)((p >> 8) & 0xFFu);
            l82 = (int)((p >> 16) & 0xFFu); l83 = (int)((p >> 24) & 0xFFu);
        } else {
            float4 r4 = *(const float4*)(x + idx);
            float4 g4 = *(const float4*)(x + idx + HW);
            float4 b4 = *(const float4*)(x + idx + 2 * HW);
            rgb2lab_px(r4.x, g4.x, b4.x, l80, A0, B0);
            rgb2lab_px(r4.y, g4.y, b4.y, l81, A1, B1);
            rgb2lab_px(r4.z, g4.z, b4.z, l82, A2, B2);
            rgb2lab_px(r4.w, g4.w, b4.w, l83, A3, B3);
        }
        apply4(lutS, col0, idx, l80, l81, l82, l83,
               A0, A1, A2, A3, B0, B1, B2, B3, wy, omwy, out);
    }
}

extern "C" void kernel_launch(void* const* d_in, const int* in_sizes, int n_in,
                              void* d_out, int out_size, void* d_ws, size_t ws_size,
                              hipStream_t stream) {
    const float* x = (const float*)d_in[0];
    float* out = (float*)d_out;
    char* ws = (char*)d_ws;
    unsigned int* hist = (unsigned int*)ws;                 // 64 KiB
    unsigned int* rowdone = (unsigned int*)(ws + 65536);    // 8 x u32
    const size_t off = 131072;
    float* Abuf = (float*)(ws + off);                       // 16 MiB
    float* Bbuf = (float*)(ws + off + (size_t)HW * 4);      // 16 MiB
    unsigned int* l8buf = (unsigned int*)(ws + off + (size_t)HW * 8); // 4 MiB
    const size_t need = off + (size_t)HW * 9;
    const int store = (ws_size >= need) ? 1 : 0;

    // mode 0 = fused register-state; 1 = fused ws-roundtrip; 2 = two-kernel.
    static int mode = -1;
    if (mode < 0) {
        int ncu = 0, dev = 0;
        (void)hipGetDevice(&dev);
        (void)hipDeviceGetAttribute(&ncu, hipDeviceAttributeMultiprocessorCount, dev);
        int nbR = 0, nbW = 0;
        bool occR = (hipOccupancyMaxActiveBlocksPerMultiprocessor(&nbR, k_fused_reg, 256, 0) == hipSuccess)
                    && (nbR * ncu >= NBLK);
        bool occW = (hipOccupancyMaxActiveBlocksPerMultiprocessor(&nbW, k_fused_ws, 256, 0) == hipSuccess)
                    && (nbW * ncu >= NBLK);
        hipFuncAttributes fa{};
        bool nospill = (hipFuncGetAttributes(&fa, (const void*)k_fused_reg) == hipSuccess)
                       && (fa.localSizeBytes == 0);
        if (occR && nospill)            mode = 0;
        else if (occW && store == 1)    mode = 1;
        else                            mode = 2;
    }

    (void)hipMemsetAsync(ws, 0, 65536 + 64, stream);   // hist + rowdone

    if (mode == 0) {
        k_fused_reg<<<NBLK, 256, 0, stream>>>(x, hist, rowdone, out);
    } else if (mode == 1) {
        k_fused_ws<<<NBLK, 256, 0, stream>>>(x, hist, rowdone, Abuf, Bbuf, l8buf, out);
    } else {
        k_hist_ab<<<NBLK, 256, 0, stream>>>(x, hist, Abuf, Bbuf, l8buf, store);
        k_lut_apply<<<NBLK, 256, 0, stream>>>(x, hist, Abuf, Bbuf, l8buf, out, store);
    }
}

// Round 7
// 128.170 us; speedup vs baseline: 1.1067x; 1.0009x over previous
//
#include <hip/hip_runtime.h>
#include <stdint.h>

#define HW 4194304      // 2048*2048
#define WIDTH 2048
#define NBLK 2048
#define F(x) ((float)(x))   // double literal -> f32, exactly like numpy scalar promotion

// ---------------------------------------------------------------------------
// Bit-exact replication of glibc sysdeps/ieee754/flt-32/s_cbrtf.c (pre-2.41)
// — what np.cbrt(float32) resolves to on the host. EMPIRICAL RULE: ALL THREE
// channels (fx, fy, fz) must use this exact path. R5 micro-opts (bit-exact,
// domain xe in [-6,1]): branchless f64 factor select + exact pow2 multiply.
// Validated: absmax unchanged (0.01171875) in R5/R6.
// ---------------------------------------------------------------------------
__device__ __forceinline__ float cbrtf_glibc(float x) {
    unsigned int bits = __float_as_uint(x);
    int xe = (int)((bits >> 23) & 0xFF) - 126;
    float xm = __uint_as_float((bits & 0x007FFFFFu) | 0x3F000000u);

    double xmd = (double)xm;
    double p = __dsub_rn(0.697570460207922770, __dmul_rn(0.191502161678719066, xmd));
    p = __dadd_rn(0.492659620528969547, __dmul_rn(p, xmd));
    float u = (float)p;

    float t2 = __fmul_rn(__fmul_rn(u, u), u);   // float, two roundings (as glibc)

    double ud  = (double)u;
    double t2d = (double)t2;
    double num = __dmul_rn(ud, __dadd_rn(t2d, __dmul_rn(2.0, xmd)));
    double den = __dadd_rn(__dmul_rn(2.0, t2d), xmd);

    int idx = 2 + (xe % 3);                     // C trunc semantics, as glibc
    double f = (idx == 2) ? 1.0
             : (idx == 0) ? (1.0 / 1.5874010519681994748)
             : (idx == 1) ? (1.0 / 1.2599210498948731648)
             : (idx == 3) ? 1.2599210498948731648
             :              1.5874010519681994748;
    double ym  = __dmul_rn(__ddiv_rn(num, den), f);
    float ymf = (float)ym;

    int q = xe / 3;                             // in {-2,-1,0} for our domain
    float s = (q == 0) ? 1.0f : ((q == -1) ? 0.5f : 0.25f);
    return __fmul_rn(ymf, s);
}

// Exact forward path — the ONLY forward path (see empirical rule above).
__device__ __forceinline__ void rgb2lab_px(float r, float g, float b,
                                           int& l8, float& A_, float& B_) {
    float X = __fadd_rn(__fadd_rn(__fmul_rn(r, F(0.412453)), __fmul_rn(g, F(0.357580))), __fmul_rn(b, F(0.180423)));
    float Y = __fadd_rn(__fadd_rn(__fmul_rn(r, F(0.212671)), __fmul_rn(g, F(0.715160))), __fmul_rn(b, F(0.072169)));
    float Z = __fadd_rn(__fadd_rn(__fmul_rn(r, F(0.019334)), __fmul_rn(g, F(0.119193))), __fmul_rn(b, F(0.950227)));
    X = __fdiv_rn(X, F(0.950456));
    Z = __fdiv_rn(Z, F(1.088754));
    const float EPS = F(0.008856);
    const float C0  = F(16.0 / 116.0);
    float fx = (X > EPS) ? cbrtf_glibc(X) : __fadd_rn(__fmul_rn(F(7.787), X), C0);
    float fy = (Y > EPS) ? cbrtf_glibc(Y) : __fadd_rn(__fmul_rn(F(7.787), Y), C0);
    float fz = (Z > EPS) ? cbrtf_glibc(Z) : __fadd_rn(__fmul_rn(F(7.787), Z), C0);
    float L  = __fsub_rn(__fmul_rn(F(116.0), fy), F(16.0));
    A_ = __fmul_rn(F(500.0), __fsub_rn(fx, fy));
    B_ = __fmul_rn(F(200.0), __fsub_rn(fy, fz));
    float Lr = rintf(__fmul_rn(L, F(255.0 / 100.0)));
    Lr = fminf(fmaxf(Lr, 0.0f), 255.0f);
    l8 = (int)Lr;
}

// lab2rgb epilogue (value-returning).
__device__ __forceinline__ void lab2rgb_px(float Leq, float A_, float B_,
                                           float& rr, float& gg, float& bb) {
    const float EPS = F(0.008856);
    const float C0  = F(16.0 / 116.0);
    float fy2 = __fdiv_rn(__fadd_rn(Leq, 16.0f), 116.0f);
    float fx2 = __fadd_rn(fy2, __fdiv_rn(A_, 500.0f));
    float fz2 = __fsub_rn(fy2, __fdiv_rn(B_, 200.0f));
    float t3;
    t3 = fx2 * fx2 * fx2;
    float X = ((t3 > EPS) ? t3 : __fdiv_rn(__fsub_rn(fx2, C0), F(7.787))) * F(0.950456);
    t3 = fy2 * fy2 * fy2;
    float Y = ((t3 > EPS) ? t3 : __fdiv_rn(__fsub_rn(fy2, C0), F(7.787))) * F(1.0);
    t3 = fz2 * fz2 * fz2;
    float Z = ((t3 > EPS) ? t3 : __fdiv_rn(__fsub_rn(fz2, C0), F(7.787))) * F(1.088754);
    rr = __fadd_rn(__fadd_rn(__fmul_rn(X, F(3.240479)),  __fmul_rn(Y, F(-1.537150))), __fmul_rn(Z, F(-0.498535)));
    gg = __fadd_rn(__fadd_rn(__fmul_rn(X, F(-0.969256)), __fmul_rn(Y, F(1.875992))),  __fmul_rn(Z, F(0.041556)));
    bb = __fadd_rn(__fadd_rn(__fmul_rn(X, F(0.055648)),  __fmul_rn(Y, F(-0.204043))), __fmul_rn(Z, F(1.057311)));
    rr = fminf(fmaxf(rr, 0.0f), 1.0f);
    gg = fminf(fmaxf(gg, 0.0f), 1.0f);
    bb = fminf(fmaxf(bb, 0.0f), 1.0f);
}

// ---------------------------------------------------------------------------
// LUT build for tile-rows (y0,y1) into lutS[4096] — R2..R6-verified BIT-EXACT
// wave-scan (partial sums are multiples of 2^-8 bounded by 2^16 => exact in
// f32 in any association => identical to reference serial cumsum).
// ---------------------------------------------------------------------------
template<bool ATOMIC_LOADS>
__device__ __forceinline__ void build_luts(const unsigned int* __restrict__ hist,
                                           float* lutS, int y0, int y1, int t) {
    const int lane = t & 63;
    const int w = t >> 6;
    #pragma unroll
    for (int i = 0; i < 4; ++i) {
        int gidx = w * 4 + i;             // 0..15
        int trow = gidx >> 3;             // 0 = y0 row, 1 = y1 row
        int tcol = gidx & 7;
        int tile = (trow ? y1 : y0) * 8 + tcol;
        float h0, h1, h2, h3;
        if (ATOMIC_LOADS) {
            const unsigned int* hp = hist + tile * 256 + lane * 4;
            h0 = (float)__hip_atomic_load(&hp[0], __ATOMIC_RELAXED, __HIP_MEMORY_SCOPE_AGENT);
            h1 = (float)__hip_atomic_load(&hp[1], __ATOMIC_RELAXED, __HIP_MEMORY_SCOPE_AGENT);
            h2 = (float)__hip_atomic_load(&hp[2], __ATOMIC_RELAXED, __HIP_MEMORY_SCOPE_AGENT);
            h3 = (float)__hip_atomic_load(&hp[3], __ATOMIC_RELAXED, __HIP_MEMORY_SCOPE_AGENT);
        } else {
            uint4 hv = *(const uint4*)(hist + tile * 256 + lane * 4);
            h0 = (float)hv.x; h1 = (float)hv.y; h2 = (float)hv.z; h3 = (float)hv.w;
        }
        float e = __fadd_rn(__fadd_rn(fmaxf(h0 - 2560.0f, 0.0f),
                                      fmaxf(h1 - 2560.0f, 0.0f)),
                            __fadd_rn(fmaxf(h2 - 2560.0f, 0.0f),
                                      fmaxf(h3 - 2560.0f, 0.0f)));
        #pragma unroll
        for (int d = 1; d < 64; d <<= 1) e = __fadd_rn(e, __shfl_xor(e, d));
        float ex = __fmul_rn(e, F(1.0 / 256.0));   // pow2 scale, exact
        float v0 = __fadd_rn(fminf(h0, 2560.0f), ex);
        float v1 = __fadd_rn(fminf(h1, 2560.0f), ex);
        float v2 = __fadd_rn(fminf(h2, 2560.0f), ex);
        float v3 = __fadd_rn(fminf(h3, 2560.0f), ex);
        float s0 = v0;
        float s1 = __fadd_rn(s0, v1);
        float s2 = __fadd_rn(s1, v2);
        float s3 = __fadd_rn(s2, v3);
        float sc = s3;
        #pragma unroll
        for (int d = 1; d < 64; d <<= 1) {
            float u2 = __shfl_up(sc, d);
            if (lane >= d) sc = __fadd_rn(sc, u2);
        }
        float excl = __fsub_rn(sc, s3);   // exact: multiples of 2^-8, <= 2^16
        int lb = trow * 2048 + tcol * 256 + lane * 4;
        float c0 = rintf(__fmul_rn(__fadd_rn(excl, s0), F(255.0 / 65536.0)));
        float c1 = rintf(__fmul_rn(__fadd_rn(excl, s1), F(255.0 / 65536.0)));
        float c2 = rintf(__fmul_rn(__fadd_rn(excl, s2), F(255.0 / 65536.0)));
        float c3 = rintf(__fmul_rn(__fadd_rn(excl, s3), F(255.0 / 65536.0)));
        lutS[lb + 0] = fminf(fmaxf(c0, 0.0f), 255.0f);
        lutS[lb + 1] = fminf(fmaxf(c1, 0.0f), 255.0f);
        lutS[lb + 2] = fminf(fmaxf(c2, 0.0f), 255.0f);
        lutS[lb + 3] = fminf(fmaxf(c3, 0.0f), 255.0f);
    }
}

// Bilinear interp + lab2rgb + float4 store for 4 px.
__device__ __forceinline__ void apply4(const float* lutS, int col0, int idx,
        int l80, int l81, int l82, int l83,
        float A0, float A1, float A2, float A3,
        float B0, float B1, float B2, float B3,
        float wy, float omwy, float* __restrict__ out) {
    float4 o_r, o_g, o_b;
#define PIX(J, L8V, AV, BV, OR_, OG_, OB_) {                                      \
    int col = col0 + (J);                                                         \
    float fxc = fminf(fmaxf(((float)col + 0.5f) * (1.0f / 256.0f) - 0.5f, 0.0f), 7.0f); \
    int xi0 = (int)floorf(fxc);                                                   \
    int xi1 = min(xi0 + 1, 7);                                                    \
    float wx = __fsub_rn(fxc, (float)xi0);                                        \
    float omwx = __fsub_rn(1.0f, wx);                                             \
    float g00 = lutS[xi0 * 256 + (L8V)];                                          \
    float g01 = lutS[xi1 * 256 + (L8V)];                                          \
    float g10 = lutS[2048 + xi0 * 256 + (L8V)];                                   \
    float g11 = lutS[2048 + xi1 * 256 + (L8V)];                                   \
    float top_ = __fadd_rn(__fmul_rn(omwx, g00), __fmul_rn(wx, g01));             \
    float bot_ = __fadd_rn(__fmul_rn(omwx, g10), __fmul_rn(wx, g11));             \
    float Leq = __fmul_rn(__fadd_rn(__fmul_rn(omwy, top_), __fmul_rn(wy, bot_)),  \
                          F(100.0 / 255.0));                                      \
    lab2rgb_px(Leq, (AV), (BV), (OR_), (OG_), (OB_));                             \
}
    PIX(0, l80, A0, B0, o_r.x, o_g.x, o_b.x);
    PIX(1, l81, A1, B1, o_r.y, o_g.y, o_b.y);
    PIX(2, l82, A2, B2, o_r.z, o_g.z, o_b.z);
    PIX(3, l83, A3, B3, o_r.w, o_g.w, o_b.w);
#undef PIX
    *(float4*)(out + idx)          = o_r;
    *(float4*)(out + idx + HW)     = o_g;
    *(float4*)(out + idx + 2 * HW) = o_b;
}

// Shared phase-1 helper for one 4-px chunk: loads, rgb2lab, LDS atomics.
// sched_barrier(0) between pixel pairs caps f64-chain interleave (register
// pressure control — R6's spill diagnosis; TLP at 32 waves/CU replaces ILP).
__device__ __forceinline__ void chunk_lab(const float* __restrict__ x,
        unsigned int* h, int rowbase, int col0,
        float& A0, float& A1, float& A2, float& A3,
        float& B0, float& B1, float& B2, float& B3, unsigned& pk) {
    const int idx = rowbase + col0;
    float4 r4 = *(const float4*)(x + idx);
    float4 g4 = *(const float4*)(x + idx + HW);
    float4 b4 = *(const float4*)(x + idx + 2 * HW);
    int l0, l1, l2, l3;
    rgb2lab_px(r4.x, g4.x, b4.x, l0, A0, B0);
    rgb2lab_px(r4.y, g4.y, b4.y, l1, A1, B1);
    __builtin_amdgcn_sched_barrier(0);
    rgb2lab_px(r4.z, g4.z, b4.z, l2, A2, B2);
    rgb2lab_px(r4.w, g4.w, b4.w, l3, A3, B3);
    __builtin_amdgcn_sched_barrier(0);
    const int hb = (col0 >> 8) << 8;   // tile uniform over the 4 px
    atomicAdd(&h[hb + l0], 1u);
    atomicAdd(&h[hb + l1], 1u);
    atomicAdd(&h[hb + l2], 1u);
    atomicAdd(&h[hb + l3], 1u);
    pk = (unsigned)l0 | ((unsigned)l1 << 8) | ((unsigned)l2 << 16) | ((unsigned)l3 << 24);
}

// Signal own tile-row done; bounded wait for the two needed tile-rows.
// R5/R6-verified device-scope pattern.
__device__ __forceinline__ void signal_and_wait(unsigned int* rowdone,
                                                int myrow, int y0, int y1, int t) {
    if (t == 0) {
        __threadfence();                                   // release hist atomics
        atomicAdd(&rowdone[myrow], 1u);                    // device-scope
        long limit = 1L << 18;                             // bounded
        while (limit-- > 0) {
            unsigned a = __hip_atomic_load(&rowdone[y0], __ATOMIC_ACQUIRE, __HIP_MEMORY_SCOPE_AGENT);
            unsigned b = __hip_atomic_load(&rowdone[y1], __ATOMIC_ACQUIRE, __HIP_MEMORY_SCOPE_AGENT);
            if (a == 256u && b == 256u) break;
            __builtin_amdgcn_s_sleep(2);
        }
    }
    __syncthreads();
}

// ===========================================================================
// Mode 0: FULL register state (16 f32 + 2 u32 across the wait). Gated on
// occupancy (2048 co-resident) AND localSizeBytes==0 (no spill).
// ===========================================================================
__global__ __launch_bounds__(256, 8) void k_fused_reg(const float* __restrict__ x,
        unsigned int* __restrict__ hist, unsigned int* __restrict__ rowdone,
        float* __restrict__ out) {
    __shared__ float lutS[4096];   // first 8 KB doubles as u32 hist in phase 1
    unsigned int* h = (unsigned int*)lutS;
    const int t = threadIdx.x;
    const int y = blockIdx.x;

    #pragma unroll
    for (int i = 0; i < 8; ++i) h[i * 256 + t] = 0;
    __syncthreads();

    const int rowbase = y * WIDTH;
    float A0, A1, A2, A3, A4, A5, A6, A7;
    float B0, B1, B2, B3, B4, B5, B6, B7;
    unsigned pk0, pk1;
    chunk_lab(x, h, rowbase, 4 * t,        A0, A1, A2, A3, B0, B1, B2, B3, pk0);
    __builtin_amdgcn_sched_barrier(0);
    chunk_lab(x, h, rowbase, 1024 + 4 * t, A4, A5, A6, A7, B4, B5, B6, B7, pk1);
    __builtin_amdgcn_sched_barrier(0);
    __syncthreads();
    {
        unsigned int* gh = hist + (y >> 8) * 2048;
        #pragma unroll
        for (int i = 0; i < 8; ++i) {
            unsigned int v = h[i * 256 + t];
            if (v) atomicAdd(&gh[i * 256 + t], v);
        }
    }
    __syncthreads();

    float fyc = fminf(fmaxf(((float)y + 0.5f) * (1.0f / 256.0f) - 0.5f, 0.0f), 7.0f);
    int y0 = (int)floorf(fyc);
    int y1 = min(y0 + 1, 7);
    float wy = __fsub_rn(fyc, (float)y0);
    float omwy = __fsub_rn(1.0f, wy);

    signal_and_wait(rowdone, y >> 8, y0, y1, t);

    build_luts<true>(hist, lutS, y0, y1, t);
    __syncthreads();

    apply4(lutS, 4 * t, rowbase + 4 * t,
           (int)(pk0 & 0xFFu), (int)((pk0 >> 8) & 0xFFu),
           (int)((pk0 >> 16) & 0xFFu), (int)((pk0 >> 24) & 0xFFu),
           A0, A1, A2, A3, B0, B1, B2, B3, wy, omwy, out);
    apply4(lutS, 1024 + 4 * t, rowbase + 1024 + 4 * t,
           (int)(pk1 & 0xFFu), (int)((pk1 >> 8) & 0xFFu),
           (int)((pk1 >> 16) & 0xFFu), (int)((pk1 >> 24) & 0xFFu),
           A4, A5, A6, A7, B4, B5, B6, B7, wy, omwy, out);
}

// ===========================================================================
// Mode 1: HALF register state (chunk 0 in regs, +9 VGPR only; chunk 1 via
// ws). Same gates. Halves the round-trip traffic if mode 0 spills.
// ===========================================================================
__global__ __launch_bounds__(256, 8) void k_fused_half(const float* __restrict__ x,
        unsigned int* __restrict__ hist, unsigned int* __restrict__ rowdone,
        float* __restrict__ Abuf, float* __restrict__ Bbuf,
        unsigned int* __restrict__ l8buf, float* __restrict__ out) {
    __shared__ float lutS[4096];
    unsigned int* h = (unsigned int*)lutS;
    const int t = threadIdx.x;
    const int y = blockIdx.x;

    #pragma unroll
    for (int i = 0; i < 8; ++i) h[i * 256 + t] = 0;
    __syncthreads();

    const int rowbase = y * WIDTH;
    float A0, A1, A2, A3, B0, B1, B2, B3;
    unsigned pk0;
    chunk_lab(x, h, rowbase, 4 * t, A0, A1, A2, A3, B0, B1, B2, B3, pk0);
    __builtin_amdgcn_sched_barrier(0);
    {
        float Aa, Ab, Ac, Ad, Ba, Bb, Bc, Bd;
        unsigned pk1;
        const int col0 = 1024 + 4 * t;
        const int idx  = rowbase + col0;
        chunk_lab(x, h, rowbase, col0, Aa, Ab, Ac, Ad, Ba, Bb, Bc, Bd, pk1);
        *(float4*)(Abuf + idx) = make_float4(Aa, Ab, Ac, Ad);
        *(float4*)(Bbuf + idx) = make_float4(Ba, Bb, Bc, Bd);
        l8buf[idx >> 2] = pk1;
    }
    __builtin_amdgcn_sched_barrier(0);
    __syncthreads();
    {
        unsigned int* gh = hist + (y >> 8) * 2048;
        #pragma unroll
        for (int i = 0; i < 8; ++i) {
            unsigned int v = h[i * 256 + t];
            if (v) atomicAdd(&gh[i * 256 + t], v);
        }
    }
    __syncthreads();

    float fyc = fminf(fmaxf(((float)y + 0.5f) * (1.0f / 256.0f) - 0.5f, 0.0f), 7.0f);
    int y0 = (int)floorf(fyc);
    int y1 = min(y0 + 1, 7);
    float wy = __fsub_rn(fyc, (float)y0);
    float omwy = __fsub_rn(1.0f, wy);

    signal_and_wait(rowdone, y >> 8, y0, y1, t);

    build_luts<true>(hist, lutS, y0, y1, t);
    __syncthreads();

    apply4(lutS, 4 * t, rowbase + 4 * t,
           (int)(pk0 & 0xFFu), (int)((pk0 >> 8) & 0xFFu),
           (int)((pk0 >> 16) & 0xFFu), (int)((pk0 >> 24) & 0xFFu),
           A0, A1, A2, A3, B0, B1, B2, B3, wy, omwy, out);
    {
        const int col0 = 1024 + 4 * t;
        const int idx  = rowbase + col0;
        float4 a4 = *(const float4*)(Abuf + idx);
        float4 b4 = *(const float4*)(Bbuf + idx);
        unsigned p = l8buf[idx >> 2];
        apply4(lutS, col0, idx,
               (int)(p & 0xFFu), (int)((p >> 8) & 0xFFu),
               (int)((p >> 16) & 0xFFu), (int)((p >> 24) & 0xFFu),
               a4.x, a4.y, a4.z, a4.w, b4.x, b4.y, b4.z, b4.w,
               wy, omwy, out);
    }
}

// ===========================================================================
// Mode 2: R5's verified fused ws-roundtrip (untouched safety net).
// ===========================================================================
__global__ __launch_bounds__(256, 8) void k_fused_ws(const float* __restrict__ x,
        unsigned int* __restrict__ hist, unsigned int* __restrict__ rowdone,
        float* __restrict__ Abuf, float* __restrict__ Bbuf,
        unsigned int* __restrict__ l8buf, float* __restrict__ out) {
    __shared__ float lutS[4096];
    unsigned int* h = (unsigned int*)lutS;
    const int t = threadIdx.x;
    const int y = blockIdx.x;

    #pragma unroll
    for (int i = 0; i < 8; ++i) h[i * 256 + t] = 0;
    __syncthreads();

    const int rowbase = y * WIDTH;
    #pragma unroll
    for (int ch = 0; ch < 2; ++ch) {
        const int col0 = ch * 1024 + 4 * t;
        const int idx  = rowbase + col0;
        float4 r4 = *(const float4*)(x + idx);
        float4 g4 = *(const float4*)(x + idx + HW);
        float4 b4 = *(const float4*)(x + idx + 2 * HW);
        int l80, l81, l82, l83;
        float A0, A1, A2, A3, B0, B1, B2, B3;
        rgb2lab_px(r4.x, g4.x, b4.x, l80, A0, B0);
        rgb2lab_px(r4.y, g4.y, b4.y, l81, A1, B1);
        rgb2lab_px(r4.z, g4.z, b4.z, l82, A2, B2);
        rgb2lab_px(r4.w, g4.w, b4.w, l83, A3, B3);
        const int hb = (col0 >> 8) << 8;
        atomicAdd(&h[hb + l80], 1u);
        atomicAdd(&h[hb + l81], 1u);
        atomicAdd(&h[hb + l82], 1u);
        atomicAdd(&h[hb + l83], 1u);
        *(float4*)(Abuf + idx) = make_float4(A0, A1, A2, A3);
        *(float4*)(Bbuf + idx) = make_float4(B0, B1, B2, B3);
        l8buf[idx >> 2] = (unsigned)l80 | ((unsigned)l81 << 8)
                        | ((unsigned)l82 << 16) | ((unsigned)l83 << 24);
    }
    __syncthreads();
    {
        unsigned int* gh = hist + (y >> 8) * 2048;
        #pragma unroll
        for (int i = 0; i < 8; ++i) {
            unsigned int v = h[i * 256 + t];
            if (v) atomicAdd(&gh[i * 256 + t], v);
        }
    }
    __syncthreads();

    float fyc = fminf(fmaxf(((float)y + 0.5f) * (1.0f / 256.0f) - 0.5f, 0.0f), 7.0f);
    int y0 = (int)floorf(fyc);
    int y1 = min(y0 + 1, 7);
    float wy = __fsub_rn(fyc, (float)y0);
    float omwy = __fsub_rn(1.0f, wy);

    signal_and_wait(rowdone, y >> 8, y0, y1, t);

    build_luts<true>(hist, lutS, y0, y1, t);
    __syncthreads();

    #pragma unroll
    for (int ch = 0; ch < 2; ++ch) {
        const int col0 = ch * 1024 + 4 * t;
        const int idx  = rowbase + col0;
        float4 a4 = *(const float4*)(Abuf + idx);
        float4 b4 = *(const float4*)(Bbuf + idx);
        unsigned p = l8buf[idx >> 2];
        apply4(lutS, col0, idx,
               (int)(p & 0xFFu), (int)((p >> 8) & 0xFFu),
               (int)((p >> 16) & 0xFFu), (int)((p >> 24) & 0xFFu),
               a4.x, a4.y, a4.z, a4.w, b4.x, b4.y, b4.z, b4.w,
               wy, omwy, out);
    }
}

// ===========================================================================
// Mode 3: two-kernel fallback (R4-verified).
// ===========================================================================
__global__ __launch_bounds__(256, 8) void k_hist_ab(const float* __restrict__ x,
        unsigned int* __restrict__ hist,
        float* __restrict__ Abuf, float* __restrict__ Bbuf,
        unsigned int* __restrict__ l8buf, int store) {
    __shared__ unsigned int h[2048];
    const int t = threadIdx.x;
    const int y = blockIdx.x;
    #pragma unroll
    for (int i = 0; i < 8; ++i) h[i * 256 + t] = 0;
    __syncthreads();

    const int rowbase = y * WIDTH;
    #pragma unroll
    for (int ch = 0; ch < 2; ++ch) {
        const int col0 = ch * 1024 + 4 * t;
        const int idx  = rowbase + col0;
        float4 r4 = *(const float4*)(x + idx);
        float4 g4 = *(const float4*)(x + idx + HW);
        float4 b4 = *(const float4*)(x + idx + 2 * HW);
        int l80, l81, l82, l83;
        float A0, A1, A2, A3, B0, B1, B2, B3;
        rgb2lab_px(r4.x, g4.x, b4.x, l80, A0, B0);
        rgb2lab_px(r4.y, g4.y, b4.y, l81, A1, B1);
        rgb2lab_px(r4.z, g4.z, b4.z, l82, A2, B2);
        rgb2lab_px(r4.w, g4.w, b4.w, l83, A3, B3);
        const int hb = (col0 >> 8) << 8;
        atomicAdd(&h[hb + l80], 1u);
        atomicAdd(&h[hb + l81], 1u);
        atomicAdd(&h[hb + l82], 1u);
        atomicAdd(&h[hb + l83], 1u);
        if (store) {
            *(float4*)(Abuf + idx) = make_float4(A0, A1, A2, A3);
            *(float4*)(Bbuf + idx) = make_float4(B0, B1, B2, B3);
            l8buf[idx >> 2] = (unsigned)l80 | ((unsigned)l81 << 8)
                            | ((unsigned)l82 << 16) | ((unsigned)l83 << 24);
        }
    }
    __syncthreads();
    unsigned int* gh = hist + (y >> 8) * 2048;
    #pragma unroll
    for (int i = 0; i < 8; ++i) {
        unsigned int v = h[i * 256 + t];
        if (v) atomicAdd(&gh[i * 256 + t], v);
    }
}

__global__ __launch_bounds__(256, 8) void k_lut_apply(const float* __restrict__ x,
        const unsigned int* __restrict__ hist,
        const float* __restrict__ Abuf, const float* __restrict__ Bbuf,
        const unsigned int* __restrict__ l8buf,
        float* __restrict__ out, int stored) {
    __shared__ float lutS[4096];
    const int t = threadIdx.x;
    const int y = blockIdx.x;

    float fyc = fminf(fmaxf(((float)y + 0.5f) * (1.0f / 256.0f) - 0.5f, 0.0f), 7.0f);
    int y0 = (int)floorf(fyc);
    int y1 = min(y0 + 1, 7);
    float wy = __fsub_rn(fyc, (float)y0);
    float omwy = __fsub_rn(1.0f, wy);

    build_luts<false>(hist, lutS, y0, y1, t);
    __syncthreads();

    const int rowbase = y * WIDTH;
    #pragma unroll
    for (int ch = 0; ch < 2; ++ch) {
        const int col0 = ch * 1024 + 4 * t;
        const int idx  = rowbase + col0;
        float A0, A1, A2, A3, B0, B1, B2, B3;
        int l80, l81, l82, l83;
        if (stored) {
            float4 a4 = *(const float4*)(Abuf + idx);
            float4 b4 = *(const float4*)(Bbuf + idx);
            unsigned p = l8buf[idx >> 2];
            A0 = a4.x; A1 = a4.y; A2 = a4.z; A3 = a4.w;
            B0 = b4.x; B1 = b4.y; B2 = b4.z; B3 = b4.w;
            l80 = (int)(p & 0xFFu); l81 = (int)((p >> 8) & 0xFFu);
            l82 = (int)((p >> 16) & 0xFFu); l83 = (int)((p >> 24) & 0xFFu);
        } else {
            float4 r4 = *(const float4*)(x + idx);
            float4 g4 = *(const float4*)(x + idx + HW);
            float4 b4 = *(const float4*)(x + idx + 2 * HW);
            rgb2lab_px(r4.x, g4.x, b4.x, l80, A0, B0);
            rgb2lab_px(r4.y, g4.y, b4.y, l81, A1, B1);
            rgb2lab_px(r4.z, g4.z, b4.z, l82, A2, B2);
            rgb2lab_px(r4.w, g4.w, b4.w, l83, A3, B3);
        }
        apply4(lutS, col0, idx, l80, l81, l82, l83,
               A0, A1, A2, A3, B0, B1, B2, B3, wy, omwy, out);
    }
}

extern "C" void kernel_launch(void* const* d_in, const int* in_sizes, int n_in,
                              void* d_out, int out_size, void* d_ws, size_t ws_size,
                              hipStream_t stream) {
    const float* x = (const float*)d_in[0];
    float* out = (float*)d_out;
    char* ws = (char*)d_ws;
    unsigned int* hist = (unsigned int*)ws;                 // 64 KiB
    unsigned int* rowdone = (unsigned int*)(ws + 65536);    // 8 x u32
    const size_t off = 131072;
    float* Abuf = (float*)(ws + off);                       // 16 MiB
    float* Bbuf = (float*)(ws + off + (size_t)HW * 4);      // 16 MiB
    unsigned int* l8buf = (unsigned int*)(ws + off + (size_t)HW * 8); // 4 MiB
    const size_t need = off + (size_t)HW * 9;
    const int store = (ws_size >= need) ? 1 : 0;

    // mode: 0=full-reg fused, 1=half-reg fused, 2=ws fused, 3=two-kernel.
    static int mode = -1;
    if (mode < 0) {
        int ncu = 0, dev = 0;
        (void)hipGetDevice(&dev);
        (void)hipDeviceGetAttribute(&ncu, hipDeviceAttributeMultiprocessorCount, dev);
        int nb = 0;
        hipFuncAttributes fa{};
        bool okReg = (hipOccupancyMaxActiveBlocksPerMultiprocessor(&nb, k_fused_reg, 256, 0) == hipSuccess)
                     && (nb * ncu >= NBLK)
                     && (hipFuncGetAttributes(&fa, (const void*)k_fused_reg) == hipSuccess)
                     && (fa.localSizeBytes == 0);
        nb = 0; fa = hipFuncAttributes{};
        bool okHalf = (hipOccupancyMaxActiveBlocksPerMultiprocessor(&nb, k_fused_half, 256, 0) == hipSuccess)
                      && (nb * ncu >= NBLK)
                      && (hipFuncGetAttributes(&fa, (const void*)k_fused_half) == hipSuccess)
                      && (fa.localSizeBytes == 0);
        nb = 0;
        bool okWs = (hipOccupancyMaxActiveBlocksPerMultiprocessor(&nb, k_fused_ws, 256, 0) == hipSuccess)
                    && (nb * ncu >= NBLK);
        if (okReg)                       mode = 0;
        else if (okHalf && store == 1)   mode = 1;
        else if (okWs && store == 1)     mode = 2;
        else                             mode = 3;
    }

    (void)hipMemsetAsync(ws, 0, 65536 + 64, stream);   // hist + rowdone

    if (mode == 0) {
        k_fused_reg<<<NBLK, 256, 0, stream>>>(x, hist, rowdone, out);
    } else if (mode == 1) {
        k_fused_half<<<NBLK, 256, 0, stream>>>(x, hist, rowdone, Abuf, Bbuf, l8buf, out);
    } else if (mode == 2) {
        k_fused_ws<<<NBLK, 256, 0, stream>>>(x, hist, rowdone, Abuf, Bbuf, l8buf, out);
    } else {
        k_hist_ab<<<NBLK, 256, 0, stream>>>(x, hist, Abuf, Bbuf, l8buf, store);
        k_lut_apply<<<NBLK, 256, 0, stream>>>(x, hist, Abuf, Bbuf, l8buf, out, store);
    }
}

// Round 8
// 127.469 us; speedup vs baseline: 1.1128x; 1.0055x over previous
//
#include <hip/hip_runtime.h>
#include <stdint.h>

#define HW 4194304      // 2048*2048
#define WIDTH 2048
#define NBLK 2048
#define F(x) ((float)(x))   // double literal -> f32, exactly like numpy scalar promotion

// ---------------------------------------------------------------------------
// Bit-exact replication of glibc sysdeps/ieee754/flt-32/s_cbrtf.c (pre-2.41)
// — what np.cbrt(float32) resolves to on the host. EMPIRICAL RULE: ALL THREE
// channels (fx, fy, fz) must use this exact path. Bit-exact micro-opts
// (validated R5-R7, absmax unchanged): branchless f64 factor select + exact
// pow2 multiply instead of ldexpf (domain xe in [-6,1]).
// ---------------------------------------------------------------------------
__device__ __forceinline__ float cbrtf_glibc(float x) {
    unsigned int bits = __float_as_uint(x);
    int xe = (int)((bits >> 23) & 0xFF) - 126;
    float xm = __uint_as_float((bits & 0x007FFFFFu) | 0x3F000000u);

    double xmd = (double)xm;
    double p = __dsub_rn(0.697570460207922770, __dmul_rn(0.191502161678719066, xmd));
    p = __dadd_rn(0.492659620528969547, __dmul_rn(p, xmd));
    float u = (float)p;

    float t2 = __fmul_rn(__fmul_rn(u, u), u);   // float, two roundings (as glibc)

    double ud  = (double)u;
    double t2d = (double)t2;
    double num = __dmul_rn(ud, __dadd_rn(t2d, __dmul_rn(2.0, xmd)));
    double den = __dadd_rn(__dmul_rn(2.0, t2d), xmd);

    int idx = 2 + (xe % 3);                     // C trunc semantics, as glibc
    double f = (idx == 2) ? 1.0
             : (idx == 0) ? (1.0 / 1.5874010519681994748)
             : (idx == 1) ? (1.0 / 1.2599210498948731648)
             : (idx == 3) ? 1.2599210498948731648
             :              1.5874010519681994748;
    double ym  = __dmul_rn(__ddiv_rn(num, den), f);
    float ymf = (float)ym;

    int q = xe / 3;                             // in {-2,-1,0} for our domain
    float s = (q == 0) ? 1.0f : ((q == -1) ? 0.5f : 0.25f);
    return __fmul_rn(ymf, s);
}

// Exact forward path — the ONLY forward path (see empirical rule above).
__device__ __forceinline__ void rgb2lab_px(float r, float g, float b,
                                           int& l8, float& A_, float& B_) {
    float X = __fadd_rn(__fadd_rn(__fmul_rn(r, F(0.412453)), __fmul_rn(g, F(0.357580))), __fmul_rn(b, F(0.180423)));
    float Y = __fadd_rn(__fadd_rn(__fmul_rn(r, F(0.212671)), __fmul_rn(g, F(0.715160))), __fmul_rn(b, F(0.072169)));
    float Z = __fadd_rn(__fadd_rn(__fmul_rn(r, F(0.019334)), __fmul_rn(g, F(0.119193))), __fmul_rn(b, F(0.950227)));
    X = __fdiv_rn(X, F(0.950456));
    Z = __fdiv_rn(Z, F(1.088754));
    const float EPS = F(0.008856);
    const float C0  = F(16.0 / 116.0);
    float fx = (X > EPS) ? cbrtf_glibc(X) : __fadd_rn(__fmul_rn(F(7.787), X), C0);
    float fy = (Y > EPS) ? cbrtf_glibc(Y) : __fadd_rn(__fmul_rn(F(7.787), Y), C0);
    float fz = (Z > EPS) ? cbrtf_glibc(Z) : __fadd_rn(__fmul_rn(F(7.787), Z), C0);
    float L  = __fsub_rn(__fmul_rn(F(116.0), fy), F(16.0));
    A_ = __fmul_rn(F(500.0), __fsub_rn(fx, fy));
    B_ = __fmul_rn(F(200.0), __fsub_rn(fy, fz));
    float Lr = rintf(__fmul_rn(L, F(255.0 / 100.0)));
    Lr = fminf(fmaxf(Lr, 0.0f), 255.0f);
    l8 = (int)Lr;
}

// lab2rgb epilogue (value-returning).
__device__ __forceinline__ void lab2rgb_px(float Leq, float A_, float B_,
                                           float& rr, float& gg, float& bb) {
    const float EPS = F(0.008856);
    const float C0  = F(16.0 / 116.0);
    float fy2 = __fdiv_rn(__fadd_rn(Leq, 16.0f), 116.0f);
    float fx2 = __fadd_rn(fy2, __fdiv_rn(A_, 500.0f));
    float fz2 = __fsub_rn(fy2, __fdiv_rn(B_, 200.0f));
    float t3;
    t3 = fx2 * fx2 * fx2;
    float X = ((t3 > EPS) ? t3 : __fdiv_rn(__fsub_rn(fx2, C0), F(7.787))) * F(0.950456);
    t3 = fy2 * fy2 * fy2;
    float Y = ((t3 > EPS) ? t3 : __fdiv_rn(__fsub_rn(fy2, C0), F(7.787))) * F(1.0);
    t3 = fz2 * fz2 * fz2;
    float Z = ((t3 > EPS) ? t3 : __fdiv_rn(__fsub_rn(fz2, C0), F(7.787))) * F(1.088754);
    rr = __fadd_rn(__fadd_rn(__fmul_rn(X, F(3.240479)),  __fmul_rn(Y, F(-1.537150))), __fmul_rn(Z, F(-0.498535)));
    gg = __fadd_rn(__fadd_rn(__fmul_rn(X, F(-0.969256)), __fmul_rn(Y, F(1.875992))),  __fmul_rn(Z, F(0.041556)));
    bb = __fadd_rn(__fadd_rn(__fmul_rn(X, F(0.055648)),  __fmul_rn(Y, F(-0.204043))), __fmul_rn(Z, F(1.057311)));
    rr = fminf(fmaxf(rr, 0.0f), 1.0f);
    gg = fminf(fmaxf(gg, 0.0f), 1.0f);
    bb = fminf(fmaxf(bb, 0.0f), 1.0f);
}

// ---------------------------------------------------------------------------
// LUT build for tile-rows (y0,y1) into lutS[4096] — R2..R7-verified BIT-EXACT
// wave-scan (partial sums are multiples of 2^-8 bounded by 2^16 => exact in
// f32 in any association => identical to reference serial cumsum).
// ---------------------------------------------------------------------------
template<bool ATOMIC_LOADS>
__device__ __forceinline__ void build_luts(const unsigned int* __restrict__ hist,
                                           float* lutS, int y0, int y1, int t) {
    const int lane = t & 63;
    const int w = t >> 6;
    #pragma unroll
    for (int i = 0; i < 4; ++i) {
        int gidx = w * 4 + i;             // 0..15
        int trow = gidx >> 3;             // 0 = y0 row, 1 = y1 row
        int tcol = gidx & 7;
        int tile = (trow ? y1 : y0) * 8 + tcol;
        float h0, h1, h2, h3;
        if (ATOMIC_LOADS) {
            const unsigned int* hp = hist + tile * 256 + lane * 4;
            h0 = (float)__hip_atomic_load(&hp[0], __ATOMIC_RELAXED, __HIP_MEMORY_SCOPE_AGENT);
            h1 = (float)__hip_atomic_load(&hp[1], __ATOMIC_RELAXED, __HIP_MEMORY_SCOPE_AGENT);
            h2 = (float)__hip_atomic_load(&hp[2], __ATOMIC_RELAXED, __HIP_MEMORY_SCOPE_AGENT);
            h3 = (float)__hip_atomic_load(&hp[3], __ATOMIC_RELAXED, __HIP_MEMORY_SCOPE_AGENT);
        } else {
            uint4 hv = *(const uint4*)(hist + tile * 256 + lane * 4);
            h0 = (float)hv.x; h1 = (float)hv.y; h2 = (float)hv.z; h3 = (float)hv.w;
        }
        float e = __fadd_rn(__fadd_rn(fmaxf(h0 - 2560.0f, 0.0f),
                                      fmaxf(h1 - 2560.0f, 0.0f)),
                            __fadd_rn(fmaxf(h2 - 2560.0f, 0.0f),
                                      fmaxf(h3 - 2560.0f, 0.0f)));
        #pragma unroll
        for (int d = 1; d < 64; d <<= 1) e = __fadd_rn(e, __shfl_xor(e, d));
        float ex = __fmul_rn(e, F(1.0 / 256.0));   // pow2 scale, exact
        float v0 = __fadd_rn(fminf(h0, 2560.0f), ex);
        float v1 = __fadd_rn(fminf(h1, 2560.0f), ex);
        float v2 = __fadd_rn(fminf(h2, 2560.0f), ex);
        float v3 = __fadd_rn(fminf(h3, 2560.0f), ex);
        float s0 = v0;
        float s1 = __fadd_rn(s0, v1);
        float s2 = __fadd_rn(s1, v2);
        float s3 = __fadd_rn(s2, v3);
        float sc = s3;
        #pragma unroll
        for (int d = 1; d < 64; d <<= 1) {
            float u2 = __shfl_up(sc, d);
            if (lane >= d) sc = __fadd_rn(sc, u2);
        }
        float excl = __fsub_rn(sc, s3);   // exact: multiples of 2^-8, <= 2^16
        int lb = trow * 2048 + tcol * 256 + lane * 4;
        float c0 = rintf(__fmul_rn(__fadd_rn(excl, s0), F(255.0 / 65536.0)));
        float c1 = rintf(__fmul_rn(__fadd_rn(excl, s1), F(255.0 / 65536.0)));
        float c2 = rintf(__fmul_rn(__fadd_rn(excl, s2), F(255.0 / 65536.0)));
        float c3 = rintf(__fmul_rn(__fadd_rn(excl, s3), F(255.0 / 65536.0)));
        lutS[lb + 0] = fminf(fmaxf(c0, 0.0f), 255.0f);
        lutS[lb + 1] = fminf(fmaxf(c1, 0.0f), 255.0f);
        lutS[lb + 2] = fminf(fmaxf(c2, 0.0f), 255.0f);
        lutS[lb + 3] = fminf(fmaxf(c3, 0.0f), 255.0f);
    }
}

// Bilinear interp + lab2rgb + float4 store for 4 px.
__device__ __forceinline__ void apply4(const float* lutS, int col0, int idx,
        int l80, int l81, int l82, int l83,
        float A0, float A1, float A2, float A3,
        float B0, float B1, float B2, float B3,
        float wy, float omwy, float* __restrict__ out) {
    float4 o_r, o_g, o_b;
#define PIX(J, L8V, AV, BV, OR_, OG_, OB_) {                                      \
    int col = col0 + (J);                                                         \
    float fxc = fminf(fmaxf(((float)col + 0.5f) * (1.0f / 256.0f) - 0.5f, 0.0f), 7.0f); \
    int xi0 = (int)floorf(fxc);                                                   \
    int xi1 = min(xi0 + 1, 7);                                                    \
    float wx = __fsub_rn(fxc, (float)xi0);                                        \
    float omwx = __fsub_rn(1.0f, wx);                                             \
    float g00 = lutS[xi0 * 256 + (L8V)];                                          \
    float g01 = lutS[xi1 * 256 + (L8V)];                                          \
    float g10 = lutS[2048 + xi0 * 256 + (L8V)];                                   \
    float g11 = lutS[2048 + xi1 * 256 + (L8V)];                                   \
    float top_ = __fadd_rn(__fmul_rn(omwx, g00), __fmul_rn(wx, g01));             \
    float bot_ = __fadd_rn(__fmul_rn(omwx, g10), __fmul_rn(wx, g11));             \
    float Leq = __fmul_rn(__fadd_rn(__fmul_rn(omwy, top_), __fmul_rn(wy, bot_)),  \
                          F(100.0 / 255.0));                                      \
    lab2rgb_px(Leq, (AV), (BV), (OR_), (OG_), (OB_));                             \
}
    PIX(0, l80, A0, B0, o_r.x, o_g.x, o_b.x);
    PIX(1, l81, A1, B1, o_r.y, o_g.y, o_b.y);
    PIX(2, l82, A2, B2, o_r.z, o_g.z, o_b.z);
    PIX(3, l83, A3, B3, o_r.w, o_g.w, o_b.w);
#undef PIX
    *(float4*)(out + idx)          = o_r;
    *(float4*)(out + idx + HW)     = o_g;
    *(float4*)(out + idx + 2 * HW) = o_b;
}

// Phase-1 helper for one 4-px chunk: loads, rgb2lab, LDS atomics.
// R8: inner sched_barriers REMOVED (they throttled ILP inside the chunk and
// didn't rescue the full-reg mode in R7). Inter-chunk fences remain at call
// sites for register-pressure control.
__device__ __forceinline__ void chunk_lab(const float* __restrict__ x,
        unsigned int* h, int rowbase, int col0,
        float& A0, float& A1, float& A2, float& A3,
        float& B0, float& B1, float& B2, float& B3, unsigned& pk) {
    const int idx = rowbase + col0;
    float4 r4 = *(const float4*)(x + idx);
    float4 g4 = *(const float4*)(x + idx + HW);
    float4 b4 = *(const float4*)(x + idx + 2 * HW);
    int l0, l1, l2, l3;
    rgb2lab_px(r4.x, g4.x, b4.x, l0, A0, B0);
    rgb2lab_px(r4.y, g4.y, b4.y, l1, A1, B1);
    rgb2lab_px(r4.z, g4.z, b4.z, l2, A2, B2);
    rgb2lab_px(r4.w, g4.w, b4.w, l3, A3, B3);
    const int hb = (col0 >> 8) << 8;   // tile uniform over the 4 px
    atomicAdd(&h[hb + l0], 1u);
    atomicAdd(&h[hb + l1], 1u);
    atomicAdd(&h[hb + l2], 1u);
    atomicAdd(&h[hb + l3], 1u);
    pk = (unsigned)l0 | ((unsigned)l1 << 8) | ((unsigned)l2 << 16) | ((unsigned)l3 << 24);
}

// Global hist merge with y-rotated sweep order: concurrently-executing
// neighbor blocks of the same tile-row start in different 1KB bin groups,
// spreading device-atomic contention across the 8KB row-hist instead of
// marching in lockstep. Pure reorder of commutative integer atomics —
// bit-identical result.
__device__ __forceinline__ void merge_hist(unsigned int* __restrict__ hist,
                                           const unsigned int* h, int y, int t) {
    unsigned int* gh = hist + (y >> 8) * 2048;
    #pragma unroll
    for (int ii = 0; ii < 8; ++ii) {
        int i = (ii + (y & 7)) & 7;
        unsigned int v = h[i * 256 + t];
        if (v) atomicAdd(&gh[i * 256 + t], v);
    }
}

// Signal own tile-row done; bounded wait for the two needed tile-rows.
// R5-R7-verified device-scope pattern.
__device__ __forceinline__ void signal_and_wait(unsigned int* rowdone,
                                                int myrow, int y0, int y1, int t) {
    if (t == 0) {
        __threadfence();                                   // release hist atomics
        atomicAdd(&rowdone[myrow], 1u);                    // device-scope
        long limit = 1L << 18;                             // bounded
        while (limit-- > 0) {
            unsigned a = __hip_atomic_load(&rowdone[y0], __ATOMIC_ACQUIRE, __HIP_MEMORY_SCOPE_AGENT);
            unsigned b = __hip_atomic_load(&rowdone[y1], __ATOMIC_ACQUIRE, __HIP_MEMORY_SCOPE_AGENT);
            if (a == 256u && b == 256u) break;
            __builtin_amdgcn_s_sleep(2);
        }
    }
    __syncthreads();
}

// ===========================================================================
// Mode 0: FULL register state (16 f32 + 2 u32 across the wait). Gated on
// occupancy (2048 co-resident) AND localSizeBytes==0 (no spill).
// ===========================================================================
__global__ __launch_bounds__(256, 8) void k_fused_reg(const float* __restrict__ x,
        unsigned int* __restrict__ hist, unsigned int* __restrict__ rowdone,
        float* __restrict__ out) {
    __shared__ float lutS[4096];   // first 8 KB doubles as u32 hist in phase 1
    unsigned int* h = (unsigned int*)lutS;
    const int t = threadIdx.x;
    const int y = blockIdx.x;

    #pragma unroll
    for (int i = 0; i < 8; ++i) h[i * 256 + t] = 0;
    __syncthreads();

    const int rowbase = y * WIDTH;
    float A0, A1, A2, A3, A4, A5, A6, A7;
    float B0, B1, B2, B3, B4, B5, B6, B7;
    unsigned pk0, pk1;
    chunk_lab(x, h, rowbase, 4 * t,        A0, A1, A2, A3, B0, B1, B2, B3, pk0);
    __builtin_amdgcn_sched_barrier(0);
    chunk_lab(x, h, rowbase, 1024 + 4 * t, A4, A5, A6, A7, B4, B5, B6, B7, pk1);
    __builtin_amdgcn_sched_barrier(0);
    __syncthreads();
    merge_hist(hist, h, y, t);
    __syncthreads();

    float fyc = fminf(fmaxf(((float)y + 0.5f) * (1.0f / 256.0f) - 0.5f, 0.0f), 7.0f);
    int y0 = (int)floorf(fyc);
    int y1 = min(y0 + 1, 7);
    float wy = __fsub_rn(fyc, (float)y0);
    float omwy = __fsub_rn(1.0f, wy);

    signal_and_wait(rowdone, y >> 8, y0, y1, t);

    build_luts<true>(hist, lutS, y0, y1, t);
    __syncthreads();

    apply4(lutS, 4 * t, rowbase + 4 * t,
           (int)(pk0 & 0xFFu), (int)((pk0 >> 8) & 0xFFu),
           (int)((pk0 >> 16) & 0xFFu), (int)((pk0 >> 24) & 0xFFu),
           A0, A1, A2, A3, B0, B1, B2, B3, wy, omwy, out);
    apply4(lutS, 1024 + 4 * t, rowbase + 1024 + 4 * t,
           (int)(pk1 & 0xFFu), (int)((pk1 >> 8) & 0xFFu),
           (int)((pk1 >> 16) & 0xFFu), (int)((pk1 >> 24) & 0xFFu),
           A4, A5, A6, A7, B4, B5, B6, B7, wy, omwy, out);
}

// ===========================================================================
// Mode 1: HALF register state (chunk 0 in regs; chunk 1 via ws). R7-verified
// (ran at 128.17, VGPR 32). R8 deltas: no inner sched_barriers, rotated merge.
// ===========================================================================
__global__ __launch_bounds__(256, 8) void k_fused_half(const float* __restrict__ x,
        unsigned int* __restrict__ hist, unsigned int* __restrict__ rowdone,
        float* __restrict__ Abuf, float* __restrict__ Bbuf,
        unsigned int* __restrict__ l8buf, float* __restrict__ out) {
    __shared__ float lutS[4096];
    unsigned int* h = (unsigned int*)lutS;
    const int t = threadIdx.x;
    const int y = blockIdx.x;

    #pragma unroll
    for (int i = 0; i < 8; ++i) h[i * 256 + t] = 0;
    __syncthreads();

    const int rowbase = y * WIDTH;
    float A0, A1, A2, A3, B0, B1, B2, B3;
    unsigned pk0;
    chunk_lab(x, h, rowbase, 4 * t, A0, A1, A2, A3, B0, B1, B2, B3, pk0);
    __builtin_amdgcn_sched_barrier(0);
    {
        float Aa, Ab, Ac, Ad, Ba, Bb, Bc, Bd;
        unsigned pk1;
        const int col0 = 1024 + 4 * t;
        const int idx  = rowbase + col0;
        chunk_lab(x, h, rowbase, col0, Aa, Ab, Ac, Ad, Ba, Bb, Bc, Bd, pk1);
        *(float4*)(Abuf + idx) = make_float4(Aa, Ab, Ac, Ad);
        *(float4*)(Bbuf + idx) = make_float4(Ba, Bb, Bc, Bd);
        l8buf[idx >> 2] = pk1;
    }
    __builtin_amdgcn_sched_barrier(0);
    __syncthreads();
    merge_hist(hist, h, y, t);
    __syncthreads();

    float fyc = fminf(fmaxf(((float)y + 0.5f) * (1.0f / 256.0f) - 0.5f, 0.0f), 7.0f);
    int y0 = (int)floorf(fyc);
    int y1 = min(y0 + 1, 7);
    float wy = __fsub_rn(fyc, (float)y0);
    float omwy = __fsub_rn(1.0f, wy);

    signal_and_wait(rowdone, y >> 8, y0, y1, t);

    build_luts<true>(hist, lutS, y0, y1, t);
    __syncthreads();

    apply4(lutS, 4 * t, rowbase + 4 * t,
           (int)(pk0 & 0xFFu), (int)((pk0 >> 8) & 0xFFu),
           (int)((pk0 >> 16) & 0xFFu), (int)((pk0 >> 24) & 0xFFu),
           A0, A1, A2, A3, B0, B1, B2, B3, wy, omwy, out);
    {
        const int col0 = 1024 + 4 * t;
        const int idx  = rowbase + col0;
        float4 a4 = *(const float4*)(Abuf + idx);
        float4 b4 = *(const float4*)(Bbuf + idx);
        unsigned p = l8buf[idx >> 2];
        apply4(lutS, col0, idx,
               (int)(p & 0xFFu), (int)((p >> 8) & 0xFFu),
               (int)((p >> 16) & 0xFFu), (int)((p >> 24) & 0xFFu),
               a4.x, a4.y, a4.z, a4.w, b4.x, b4.y, b4.z, b4.w,
               wy, omwy, out);
    }
}

// ===========================================================================
// Mode 2: fused ws-roundtrip (R5-verified safety net).
// ===========================================================================
__global__ __launch_bounds__(256, 8) void k_fused_ws(const float* __restrict__ x,
        unsigned int* __restrict__ hist, unsigned int* __restrict__ rowdone,
        float* __restrict__ Abuf, float* __restrict__ Bbuf,
        unsigned int* __restrict__ l8buf, float* __restrict__ out) {
    __shared__ float lutS[4096];
    unsigned int* h = (unsigned int*)lutS;
    const int t = threadIdx.x;
    const int y = blockIdx.x;

    #pragma unroll
    for (int i = 0; i < 8; ++i) h[i * 256 + t] = 0;
    __syncthreads();

    const int rowbase = y * WIDTH;
    #pragma unroll
    for (int ch = 0; ch < 2; ++ch) {
        const int col0 = ch * 1024 + 4 * t;
        const int idx  = rowbase + col0;
        float A0, A1, A2, A3, B0, B1, B2, B3;
        unsigned pk;
        chunk_lab(x, h, rowbase, col0, A0, A1, A2, A3, B0, B1, B2, B3, pk);
        *(float4*)(Abuf + idx) = make_float4(A0, A1, A2, A3);
        *(float4*)(Bbuf + idx) = make_float4(B0, B1, B2, B3);
        l8buf[idx >> 2] = pk;
    }
    __syncthreads();
    merge_hist(hist, h, y, t);
    __syncthreads();

    float fyc = fminf(fmaxf(((float)y + 0.5f) * (1.0f / 256.0f) - 0.5f, 0.0f), 7.0f);
    int y0 = (int)floorf(fyc);
    int y1 = min(y0 + 1, 7);
    float wy = __fsub_rn(fyc, (float)y0);
    float omwy = __fsub_rn(1.0f, wy);

    signal_and_wait(rowdone, y >> 8, y0, y1, t);

    build_luts<true>(hist, lutS, y0, y1, t);
    __syncthreads();

    #pragma unroll
    for (int ch = 0; ch < 2; ++ch) {
        const int col0 = ch * 1024 + 4 * t;
        const int idx  = rowbase + col0;
        float4 a4 = *(const float4*)(Abuf + idx);
        float4 b4 = *(const float4*)(Bbuf + idx);
        unsigned p = l8buf[idx >> 2];
        apply4(lutS, col0, idx,
               (int)(p & 0xFFu), (int)((p >> 8) & 0xFFu),
               (int)((p >> 16) & 0xFFu), (int)((p >> 24) & 0xFFu),
               a4.x, a4.y, a4.z, a4.w, b4.x, b4.y, b4.z, b4.w,
               wy, omwy, out);
    }
}

// ===========================================================================
// Mode 3: two-kernel fallback (R4-verified).
// ===========================================================================
__global__ __launch_bounds__(256, 8) void k_hist_ab(const float* __restrict__ x,
        unsigned int* __restrict__ hist,
        float* __restrict__ Abuf, float* __restrict__ Bbuf,
        unsigned int* __restrict__ l8buf, int store) {
    __shared__ unsigned int h[2048];
    const int t = threadIdx.x;
    const int y = blockIdx.x;
    #pragma unroll
    for (int i = 0; i < 8; ++i) h[i * 256 + t] = 0;
    __syncthreads();

    const int rowbase = y * WIDTH;
    #pragma unroll
    for (int ch = 0; ch < 2; ++ch) {
        const int col0 = ch * 1024 + 4 * t;
        const int idx  = rowbase + col0;
        float A0, A1, A2, A3, B0, B1, B2, B3;
        unsigned pk;
        chunk_lab(x, h, rowbase, col0, A0, A1, A2, A3, B0, B1, B2, B3, pk);
        if (store) {
            *(float4*)(Abuf + idx) = make_float4(A0, A1, A2, A3);
            *(float4*)(Bbuf + idx) = make_float4(B0, B1, B2, B3);
            l8buf[idx >> 2] = pk;
        }
    }
    __syncthreads();
    merge_hist(hist, h, y, t);
}

__global__ __launch_bounds__(256, 8) void k_lut_apply(const float* __restrict__ x,
        const unsigned int* __restrict__ hist,
        const float* __restrict__ Abuf, const float* __restrict__ Bbuf,
        const unsigned int* __restrict__ l8buf,
        float* __restrict__ out, int stored) {
    __shared__ float lutS[4096];
    const int t = threadIdx.x;
    const int y = blockIdx.x;

    float fyc = fminf(fmaxf(((float)y + 0.5f) * (1.0f / 256.0f) - 0.5f, 0.0f), 7.0f);
    int y0 = (int)floorf(fyc);
    int y1 = min(y0 + 1, 7);
    float wy = __fsub_rn(fyc, (float)y0);
    float omwy = __fsub_rn(1.0f, wy);

    build_luts<false>(hist, lutS, y0, y1, t);
    __syncthreads();

    const int rowbase = y * WIDTH;
    #pragma unroll
    for (int ch = 0; ch < 2; ++ch) {
        const int col0 = ch * 1024 + 4 * t;
        const int idx  = rowbase + col0;
        float A0, A1, A2, A3, B0, B1, B2, B3;
        int l80, l81, l82, l83;
        if (stored) {
            float4 a4 = *(const float4*)(Abuf + idx);
            float4 b4 = *(const float4*)(Bbuf + idx);
            unsigned p = l8buf[idx >> 2];
            A0 = a4.x; A1 = a4.y; A2 = a4.z; A3 = a4.w;
            B0 = b4.x; B1 = b4.y; B2 = b4.z; B3 = b4.w;
            l80 = (int)(p & 0xFFu); l81 = (int)((p >> 8) & 0xFFu);
            l82 = (int)((p >> 16) & 0xFFu); l83 = (int)((p >> 24) & 0xFFu);
        } else {
            float4 r4 = *(const float4*)(x + idx);
            float4 g4 = *(const float4*)(x + idx + HW);
            float4 b4 = *(const float4*)(x + idx + 2 * HW);
            rgb2lab_px(r4.x, g4.x, b4.x, l80, A0, B0);
            rgb2lab_px(r4.y, g4.y, b4.y, l81, A1, B1);
            rgb2lab_px(r4.z, g4.z, b4.z, l82, A2, B2);
            rgb2lab_px(r4.w, g4.w, b4.w, l83, A3, B3);
        }
        apply4(lutS, col0, idx, l80, l81, l82, l83,
               A0, A1, A2, A3, B0, B1, B2, B3, wy, omwy, out);
    }
}

extern "C" void kernel_launch(void* const* d_in, const int* in_sizes, int n_in,
                              void* d_out, int out_size, void* d_ws, size_t ws_size,
                              hipStream_t stream) {
    const float* x = (const float*)d_in[0];
    float* out = (float*)d_out;
    char* ws = (char*)d_ws;
    unsigned int* hist = (unsigned int*)ws;                 // 64 KiB
    unsigned int* rowdone = (unsigned int*)(ws + 65536);    // 8 x u32
    const size_t off = 131072;
    float* Abuf = (float*)(ws + off);                       // 16 MiB
    float* Bbuf = (float*)(ws + off + (size_t)HW * 4);      // 16 MiB
    unsigned int* l8buf = (unsigned int*)(ws + off + (size_t)HW * 8); // 4 MiB
    const size_t need = off + (size_t)HW * 9;
    const int store = (ws_size >= need) ? 1 : 0;

    // mode: 0=full-reg fused, 1=half-reg fused, 2=ws fused, 3=two-kernel.
    static int mode = -1;
    if (mode < 0) {
        int ncu = 0, dev = 0;
        (void)hipGetDevice(&dev);
        (void)hipDeviceGetAttribute(&ncu, hipDeviceAttributeMultiprocessorCount, dev);
        int nb = 0;
        hipFuncAttributes fa{};
        bool okReg = (hipOccupancyMaxActiveBlocksPerMultiprocessor(&nb, k_fused_reg, 256, 0) == hipSuccess)
                     && (nb * ncu >= NBLK)
                     && (hipFuncGetAttributes(&fa, (const void*)k_fused_reg) == hipSuccess)
                     && (fa.localSizeBytes == 0);
        nb = 0; fa = hipFuncAttributes{};
        bool okHalf = (hipOccupancyMaxActiveBlocksPerMultiprocessor(&nb, k_fused_half, 256, 0) == hipSuccess)
                      && (nb * ncu >= NBLK)
                      && (hipFuncGetAttributes(&fa, (const void*)k_fused_half) == hipSuccess)
                      && (fa.localSizeBytes == 0);
        nb = 0;
        bool okWs = (hipOccupancyMaxActiveBlocksPerMultiprocessor(&nb, k_fused_ws, 256, 0) == hipSuccess)
                    && (nb * ncu >= NBLK);
        if (okReg)                       mode = 0;
        else if (okHalf && store == 1)   mode = 1;
        else if (okWs && store == 1)     mode = 2;
        else                             mode = 3;
    }

    (void)hipMemsetAsync(ws, 0, 65536 + 64, stream);   // hist + rowdone

    if (mode == 0) {
        k_fused_reg<<<NBLK, 256, 0, stream>>>(x, hist, rowdone, out);
    } else if (mode == 1) {
        k_fused_half<<<NBLK, 256, 0, stream>>>(x, hist, rowdone, Abuf, Bbuf, l8buf, out);
    } else if (mode == 2) {
        k_fused_ws<<<NBLK, 256, 0, stream>>>(x, hist, rowdone, Abuf, Bbuf, l8buf, out);
    } else {
        k_hist_ab<<<NBLK, 256, 0, stream>>>(x, hist, Abuf, Bbuf, l8buf, store);
        k_lut_apply<<<NBLK, 256, 0, stream>>>(x, hist, Abuf, Bbuf, l8buf, out, store);
    }
}